// Round 12
// baseline (490.166 us; speedup 1.0000x reference)
//
#include <hip/hip_runtime.h>
#include <math.h>

#define Bn 2
#define Hn 12
#define Tn 512
#define Cn 768
#define HS 64
#define BH 24
#define MTOP 8
#define NCOMB 36
#define NEGV -1e30f

#define NX (Bn * Tn * Cn)     // 786432
#define NW (3 * Cn * Cn)      // 1769472
#define NP (Cn * Cn)          // 589824

typedef __bf16 bf16x8 __attribute__((ext_vector_type(8)));
typedef float f32x4 __attribute__((ext_vector_type(4)));

__device__ __constant__ int C_SL0[NCOMB] = {
  0,1,2,3,4,5,6,7,
  0,0,0,0,0,0,0,
  1,1,1,1,1,1,
  2,2,2,2,2,
  3,3,3,3,
  4,4,4,
  5,5,
  6};
__device__ __constant__ int C_SL1[NCOMB] = {
  -1,-1,-1,-1,-1,-1,-1,-1,
  1,2,3,4,5,6,7,
  2,3,4,5,6,7,
  3,4,5,6,7,
  4,5,6,7,
  5,6,7,
  6,7,
  7};

__device__ __constant__ int PA[45] = {
  0,0,0,0,0,0,0,0,0,
  1,1,1,1,1,1,1,1,
  2,2,2,2,2,2,2,
  3,3,3,3,3,3,
  4,4,4,4,4,
  5,5,5,5,
  6,6,6,
  7,7,
  8};
__device__ __constant__ int PB[45] = {
  0,1,2,3,4,5,6,7,8,
  1,2,3,4,5,6,7,8,
  2,3,4,5,6,7,8,
  3,4,5,6,7,8,
  4,5,6,7,8,
  5,6,7,8,
  6,7,8,
  7,8,
  8};

// lower-triangle 8x8 tile enumeration (ti >= tj)
__device__ __constant__ int TI[36] = {
  0,1,1,2,2,2,3,3,3,3,4,4,4,4,4,5,5,5,5,5,5,6,6,6,6,6,6,6,7,7,7,7,7,7,7,7};
__device__ __constant__ int TJ[36] = {
  0,0,1,0,1,2,0,1,2,3,0,1,2,3,4,0,1,2,3,4,5,0,1,2,3,4,5,6,0,1,2,3,4,5,6,7};

__device__ __forceinline__ unsigned short bf_rne(float x) {
    unsigned u = __float_as_uint(x);
    return (unsigned short)((u + 0x7fff + ((u >> 16) & 1)) >> 16);
}
__device__ __forceinline__ float bf_f(unsigned short s) {
    return __uint_as_float(((unsigned)s) << 16);
}

// ---- fused conversions: xcat | Wcat | Wpbf in one launch -----------------------------
__global__ __launch_bounds__(256) void conv_all(const float* __restrict__ x,
                                                const float* __restrict__ Wa,
                                                const float* __restrict__ Wp,
                                                unsigned short* __restrict__ xcat,
                                                unsigned short* __restrict__ Wcat,
                                                unsigned short* __restrict__ Wpbf) {
    int idx = blockIdx.x * 256 + threadIdx.x;
    if (idx < NX) {
        int r = idx / Cn, c = idx - r * Cn;
        float v = x[idx];
        unsigned short h = bf_rne(v);
        unsigned short l = bf_rne(v - bf_f(h));
        size_t base = (size_t)r * 2304 + c;
        xcat[base] = h;            // [xhi | xhi | xlo]
        xcat[base + 768] = h;
        xcat[base + 1536] = l;
    } else if (idx < NX + NW) {
        int j = idx - NX;
        int r = j / Cn, c = j - r * Cn;
        float v = Wa[j];
        unsigned short h = bf_rne(v);
        unsigned short l = bf_rne(v - bf_f(h));
        size_t base = (size_t)r * 2304 + c;
        Wcat[base] = h;            // [Whi | Wlo | Whi]
        Wcat[base + 1536] = h;
        Wcat[base + 768] = l;
    } else if (idx < NX + NW + NP) {
        int j = idx - NX - NW;
        Wpbf[j] = bf_rne(Wp[j]);
    }
}

// ---- shared LDS-staged bf16 NT GEMM core, prefetch depth 2 ---------------------------
// Kst = row stride (elems); extent = NS*64 <= Kst. NS >= 2 required (always true here).
// Depth-2 register pipeline: loads for slab s+2 issue at slab s -> ~2 slabs of latency
// budget, removing the vmcnt stall that made depth-1 latency-bound (r11 post-mortem).
__device__ __forceinline__ void gemm_core(const unsigned short* __restrict__ Ag,
                                          const unsigned short* __restrict__ Bg,
                                          int Kst, int NS,
                                          unsigned short* Ab, unsigned short* Bb,
                                          f32x4 acc[2][2]) {
    const int tid = threadIdx.x;
    const int wv = tid >> 6, lane = tid & 63;
    const int r0 = tid >> 3;
    const int c8 = (tid & 7) * 8;
    const int m0w = (wv >> 1) * 32;
    const int n0w = (wv & 1) * 32;
    const int fr = lane & 15;
    const int fk = (lane >> 4) * 8;

    const unsigned short* pa0 = Ag + (size_t)r0 * Kst + c8;
    const unsigned short* pa1 = Ag + (size_t)(r0 + 32) * Kst + c8;
    const unsigned short* pb0 = Bg + (size_t)r0 * Kst + c8;
    const unsigned short* pb1 = Bg + (size_t)(r0 + 32) * Kst + c8;

    bf16x8 ra0[2], ra1[2], rb0[2], rb1[2];
    ra0[0] = *(const bf16x8*)pa0;        ra1[0] = *(const bf16x8*)pa1;
    rb0[0] = *(const bf16x8*)pb0;        rb1[0] = *(const bf16x8*)pb1;
    ra0[1] = *(const bf16x8*)(pa0 + 64); ra1[1] = *(const bf16x8*)(pa1 + 64);
    rb0[1] = *(const bf16x8*)(pb0 + 64); rb1[1] = *(const bf16x8*)(pb1 + 64);

    const int sO = r0 * 72 + c8;
    for (int s = 0; s < NS; ++s) {
        const int p = s & 1;
        const int bufo = p * 4608;
        *(bf16x8*)(Ab + bufo + sO) = ra0[p];
        *(bf16x8*)(Ab + bufo + sO + 32 * 72) = ra1[p];
        *(bf16x8*)(Bb + bufo + sO) = rb0[p];
        *(bf16x8*)(Bb + bufo + sO + 32 * 72) = rb1[p];
        __syncthreads();
        if (s + 2 < NS) {
            ra0[p] = *(const bf16x8*)(pa0 + (s + 2) * 64);
            ra1[p] = *(const bf16x8*)(pa1 + (s + 2) * 64);
            rb0[p] = *(const bf16x8*)(pb0 + (s + 2) * 64);
            rb1[p] = *(const bf16x8*)(pb1 + (s + 2) * 64);
        }
        #pragma unroll
        for (int ks = 0; ks < 2; ++ks) {
            bf16x8 af[2], bg[2];
            #pragma unroll
            for (int mi = 0; mi < 2; ++mi)
                af[mi] = *(const bf16x8*)(Ab + bufo + (m0w + 16 * mi + fr) * 72 + ks * 32 + fk);
            #pragma unroll
            for (int ni = 0; ni < 2; ++ni)
                bg[ni] = *(const bf16x8*)(Bb + bufo + (n0w + 16 * ni + fr) * 72 + ks * 32 + fk);
            #pragma unroll
            for (int mi = 0; mi < 2; ++mi)
                #pragma unroll
                for (int ni = 0; ni < 2; ++ni)
                    acc[mi][ni] = __builtin_amdgcn_mfma_f32_16x16x32_bf16(af[mi], bg[ni], acc[mi][ni], 0, 0, 0);
        }
    }
}

// ---- qkv fused: by<24 -> q/k 3-term GEMM (K'=2304); by>=24 -> v 1-term (K=768) -------
__global__ __launch_bounds__(256) void mfma_qkv(const unsigned short* __restrict__ xcat,
                                                const unsigned short* __restrict__ Wcat,
                                                const float* __restrict__ bias,
                                                unsigned short* __restrict__ qcat,
                                                unsigned short* __restrict__ kcat,
                                                float* __restrict__ vh) {
    __shared__ unsigned short Ab[2 * 64 * 72];
    __shared__ unsigned short Bb[2 * 64 * 72];
    const int tm = blockIdx.x * 64;
    const int by = blockIdx.y;
    const int wv = threadIdx.x >> 6, lane = threadIdx.x & 63;
    const int kq = lane >> 4, r = lane & 15;
    f32x4 acc[2][2] = {};

    if (by < 24) {
        const int tn = by * 64;
        gemm_core(xcat + (size_t)tm * 2304, Wcat + (size_t)tn * 2304, 2304, 36, Ab, Bb, acc);
        const int part = tn / Cn;          // 0=q, 1=k
        #pragma unroll
        for (int mi = 0; mi < 2; ++mi) {
            #pragma unroll
            for (int ni = 0; ni < 2; ++ni) {
                #pragma unroll
                for (int rr = 0; rr < 4; ++rr) {
                    int mm = tm + (wv >> 1) * 32 + mi * 16 + kq * 4 + rr;
                    int nn = tn + (wv & 1) * 32 + ni * 16 + r;
                    float val = acc[mi][ni][rr] + bias[nn];
                    int bb = mm >> 9, t = mm & 511;
                    int c = nn - part * Cn;
                    int h = c >> 6, d = c & 63;
                    int bh = bb * Hn + h;
                    unsigned short s1 = bf_rne(val);
                    float r1 = val - bf_f(s1);
                    unsigned short s2 = bf_rne(r1);
                    unsigned short s3 = bf_rne(r1 - bf_f(s2));
                    size_t base = ((size_t)bh * Tn + t) * 384 + d;
                    if (part == 0) {   // qcat = [q1|q1|q2|q1|q3|q2]
                        qcat[base]       = s1;
                        qcat[base + 64]  = s1;
                        qcat[base + 192] = s1;
                        qcat[base + 128] = s2;
                        qcat[base + 320] = s2;
                        qcat[base + 256] = s3;
                    } else {           // kcat = [k1|k2|k1|k3|k1|k2]
                        kcat[base]       = s1;
                        kcat[base + 128] = s1;
                        kcat[base + 256] = s1;
                        kcat[base + 64]  = s2;
                        kcat[base + 320] = s2;
                        kcat[base + 192] = s3;
                    }
                }
            }
        }
    } else {
        // v: single-term bf16 (xhi @ Wvhi^T), K extent 768 within stride-2304 rows
        const int hvi = by - 24;           // head-col tile 0..11
        const int cv = hvi * 64;
        gemm_core(xcat + (size_t)tm * 2304,
                  Wcat + (size_t)(1536 + cv) * 2304, 2304, 12, Ab, Bb, acc);
        #pragma unroll
        for (int mi = 0; mi < 2; ++mi) {
            #pragma unroll
            for (int ni = 0; ni < 2; ++ni) {
                #pragma unroll
                for (int rr = 0; rr < 4; ++rr) {
                    int mm = tm + (wv >> 1) * 32 + mi * 16 + kq * 4 + rr;
                    int nloc = (wv & 1) * 32 + ni * 16 + r;      // 0..63 == d
                    float val = acc[mi][ni][rr] + bias[1536 + cv + nloc];
                    int bb = mm >> 9, t = mm & 511;
                    int bh = bb * Hn + hvi;
                    vh[((size_t)bh * Tn + t) * HS + nloc] = val;
                }
            }
        }
    }
}

// ---- sim: S = qcat @ kcat^T per bh (K'=384 = 6-term split), triangle tiles -----------
__global__ __launch_bounds__(256) void mfma_sim(const unsigned short* __restrict__ qcat,
                                                const unsigned short* __restrict__ kcat,
                                                float* __restrict__ S) {
    __shared__ unsigned short Ab[2 * 64 * 72];
    __shared__ unsigned short Bb[2 * 64 * 72];
    const int bh = blockIdx.y;
    const int ti = TI[blockIdx.x], tj = TJ[blockIdx.x];
    f32x4 acc[2][2] = {};
    gemm_core(qcat + ((size_t)bh * Tn + ti * 64) * 384,
              kcat + ((size_t)bh * Tn + tj * 64) * 384, 384, 6, Ab, Bb, acc);

    const int wv = threadIdx.x >> 6, lane = threadIdx.x & 63;
    const int kq = lane >> 4, r = lane & 15;
    float* Sp = S + (size_t)bh * 147456 + (size_t)(ti * (ti + 1) / 2 + tj) * 4096;
    #pragma unroll
    for (int mi = 0; mi < 2; ++mi)
        #pragma unroll
        for (int ni = 0; ni < 2; ++ni)
            #pragma unroll
            for (int rr = 0; rr < 4; ++rr) {
                int ml = (wv >> 1) * 32 + mi * 16 + kq * 4 + rr;
                int nl = (wv & 1) * 32 + ni * 16 + r;
                Sp[ml * 64 + nl] = acc[mi][ni][rr];
            }
}

// ---- proj: out = ybf @ Wpbf^T + bias (K=768) -----------------------------------------
__global__ __launch_bounds__(256) void mfma_proj(const unsigned short* __restrict__ Abf,
                                                 const unsigned short* __restrict__ Bbf,
                                                 const float* __restrict__ bias,
                                                 float* __restrict__ outp) {
    __shared__ unsigned short Ab[2 * 64 * 72];
    __shared__ unsigned short Bb[2 * 64 * 72];
    const int tm = blockIdx.x * 64;
    const int tn = blockIdx.y * 64;
    f32x4 acc[2][2] = {};
    gemm_core(Abf + (size_t)tm * Cn, Bbf + (size_t)tn * Cn, Cn, 12, Ab, Bb, acc);

    const int wv = threadIdx.x >> 6, lane = threadIdx.x & 63;
    const int kq = lane >> 4, r = lane & 15;
    #pragma unroll
    for (int mi = 0; mi < 2; ++mi)
        #pragma unroll
        for (int ni = 0; ni < 2; ++ni)
            #pragma unroll
            for (int rr = 0; rr < 4; ++rr) {
                int mm = tm + (wv >> 1) * 32 + mi * 16 + kq * 4 + rr;
                int nn = tn + (wv & 1) * 32 + ni * 16 + r;
                outp[(size_t)mm * Cn + nn] = acc[mi][ni][rr] + bias[nn];
            }
}

// ---- DPP selection: TWO tokens per wave; coef-collapsed epilogue ---------------------
__global__ __launch_bounds__(256) void dpp_kernel(const float* __restrict__ S,
                                                  const unsigned short* __restrict__ kcat,
                                                  const float* __restrict__ vh,
                                                  unsigned short* __restrict__ yb) {
    const int bh = blockIdx.x;
    const int w = threadIdx.x >> 6;
    const int lane = threadIdx.x & 63;
    const int ibase = blockIdx.y * 8 + w * 2;

    __shared__ float KshW[8][9][68];   // 19584 B
    __shared__ float VshW[8][9][65];   // 18720 B
    __shared__ float Gsh[8][81];       //  2592 B
    __shared__ float qdsh[8][12];      //   384 B  -> 41280 B total
    const float* Sbh = S + (size_t)bh * 147456;
    const unsigned short* kc = kcat + (size_t)bh * Tn * 384;
    const float* vbase = vh + (size_t)bh * Tn * HS;

    int ii[2], tib[2];
    float sv[2][8];
    #pragma unroll
    for (int tt = 0; tt < 2; ++tt) {
        const int i = ibase + tt;
        ii[tt] = i;
        const int t8 = i >> 6;
        tib[tt] = t8;
        const int tribase = t8 * (t8 + 1) / 2;
        const int rloc = (i & 63) * 64;
        #pragma unroll
        for (int rr = 0; rr < 8; ++rr) {
            sv[tt][rr] = -INFINITY;
            if (rr <= t8) {
                int j = rr * 64 + lane;
                float s = Sbh[(size_t)(tribase + rr) * 4096 + rloc + lane];
                sv[tt][rr] = (j <= i) ? s : -INFINITY;
            }
        }
    }

    // qd0 = sim[i][i]
    float qd0[2] = {0.f, 0.f};
    #pragma unroll
    for (int c = 0; c < 8; ++c)
        #pragma unroll
        for (int tt = 0; tt < 2; ++tt) {
            float t = __shfl(sv[tt][c], ii[tt] & 63, 64);
            if (c == tib[tt]) qd0[tt] = t;
        }

    // top-8: 8 passes, two interleaved butterflies (value desc, tie -> lower index)
    float topv[2][8]; int topi[2][8];
    #pragma unroll
    for (int p = 0; p < MTOP; ++p) {
        float bv[2]; int bi[2];
        #pragma unroll
        for (int tt = 0; tt < 2; ++tt) {
            bv[tt] = -INFINITY; bi[tt] = 0x7fffffff;
            #pragma unroll
            for (int r = 0; r < 8; ++r) {
                int j = r * 64 + lane;
                float v = sv[tt][r];
                if (v > bv[tt] || (v == bv[tt] && j < bi[tt])) { bv[tt] = v; bi[tt] = j; }
            }
        }
        #pragma unroll
        for (int off = 32; off > 0; off >>= 1)
            #pragma unroll
            for (int tt = 0; tt < 2; ++tt) {
                float ov = __shfl_xor(bv[tt], off, 64);
                int   oi = __shfl_xor(bi[tt], off, 64);
                if (ov > bv[tt] || (ov == bv[tt] && oi < bi[tt])) { bv[tt] = ov; bi[tt] = oi; }
            }
        #pragma unroll
        for (int tt = 0; tt < 2; ++tt) {
            topv[tt][p] = bv[tt]; topi[tt][p] = bi[tt];
            const int rs = bi[tt] >> 6, ls = bi[tt] & 63;
            #pragma unroll
            for (int r = 0; r < 8; ++r)
                if (r == rs && lane == ls) sv[tt][r] = -INFINITY;
        }
    }

    // stage K/V rows for both contexts
    #pragma unroll
    for (int tt = 0; tt < 2; ++tt) {
        const int ctx = w * 2 + tt;
        #pragma unroll
        for (int a = 0; a < 9; ++a) {
            int t = (a == 0) ? ii[tt] : topi[tt][a - 1];
            size_t kb = (size_t)t * 384 + lane;
            KshW[ctx][a][lane] = bf_f(kc[kb]) + bf_f(kc[kb + 64]) + bf_f(kc[kb + 192]);
            VshW[ctx][a][lane] = vbase[(size_t)t * HS + lane];
        }
        if (lane < 9) {
            float val = qd0[tt];
            #pragma unroll
            for (int p = 0; p < 8; ++p) if (lane == p + 1) val = topv[tt][p];
            qdsh[ctx][lane] = val;
        }
    }

    // gram for both contexts
    if (lane < 45) {
        const int a = PA[lane], b = PB[lane];
        #pragma unroll
        for (int tt = 0; tt < 2; ++tt) {
            const int ctx = w * 2 + tt;
            const float4* rka = (const float4*)&KshW[ctx][a][0];
            const float4* rkb = (const float4*)&KshW[ctx][b][0];
            float acc = 0.f;
            #pragma unroll
            for (int t = 0; t < 16; ++t) {
                float4 fa = rka[t], fb = rkb[t];
                acc += fa.x * fb.x; acc += fa.y * fb.y;
                acc += fa.z * fb.z; acc += fa.w * fb.w;
            }
            Gsh[ctx][a * 9 + b] = acc;
            Gsh[ctx][b * 9 + a] = acc;
        }
    }

    // combos (lanes 0..35)
    const int sl0c = (lane < NCOMB) ? C_SL0[lane] : -1;
    const int sl1c = (lane < NCOMB) ? C_SL1[lane] : -1;
    float score[2]; int ca[2], cb[2], sdim[2];
    #pragma unroll
    for (int tt = 0; tt < 2; ++tt) {
        const int ctx = w * 2 + tt;
        const int i = ii[tt];
        const int n_cand = (i + 1 < MTOP) ? (i + 1) : MTOP;
        int vmask = 0;
        #pragma unroll
        for (int s = 0; s < MTOP; ++s)
            if (s < n_cand && topi[tt][s] != i) vmask |= (1 << s);

        score[tt] = -INFINITY; ca[tt] = 0; cb[tt] = 0; sdim[tt] = 1;
        if (lane < NCOMB) {
            sdim[tt] = (sl1c < 0) ? 1 : 2;
            ca[tt] = sl0c + 1;
            cb[tt] = (sl1c < 0) ? 0 : sl1c + 1;
            bool valid = ((vmask >> sl0c) & 1);
            if (sdim[tt] == 2) valid = valid && ((vmask >> sl1c) & 1);
            float G00 = Gsh[ctx][0];
            float Gaa = Gsh[ctx][ca[tt] * 9 + ca[tt]];
            float G0a = Gsh[ctx][ca[tt]];
            float det;
            if (sdim[tt] == 1) {
                det = G00 * Gaa - G0a * G0a;
            } else {
                float G0b = Gsh[ctx][cb[tt]];
                float Gab = Gsh[ctx][ca[tt] * 9 + cb[tt]];
                float Gbb = Gsh[ctx][cb[tt] * 9 + cb[tt]];
                det = G00 * (Gaa * Gbb - Gab * Gab)
                    - G0a * (G0a * Gbb - Gab * G0b)
                    + G0b * (G0a * Gab - Gaa * G0b);
            }
            score[tt] = valid ? (logf(det + 1e-6f) / (float)(sdim[tt] + 1)) : NEGV;
        }
    }

    float mx[2] = {score[0], score[1]};
    #pragma unroll
    for (int off = 32; off > 0; off >>= 1)
        #pragma unroll
        for (int tt = 0; tt < 2; ++tt)
            mx[tt] = fmaxf(mx[tt], __shfl_xor(mx[tt], off, 64));
    float ee[2];
    #pragma unroll
    for (int tt = 0; tt < 2; ++tt)
        ee[tt] = (lane < NCOMB) ? expf(score[tt] - mx[tt]) : 0.f;
    float sum[2] = {ee[0], ee[1]};
    #pragma unroll
    for (int off = 32; off > 0; off >>= 1)
        #pragma unroll
        for (int tt = 0; tt < 2; ++tt)
            sum[tt] += __shfl_xor(sum[tt], off, 64);

    // per-lane prob-folded attention weights
    float pwx[2] = {0.f, 0.f}, pwy[2] = {0.f, 0.f}, pwz[2] = {0.f, 0.f};
    #pragma unroll
    for (int tt = 0; tt < 2; ++tt) {
        const int ctx = w * 2 + tt;
        if (lane < NCOMB) {
            float prob = ee[tt] / sum[tt];
            float d0 = qdsh[ctx][0]      * 0.125f;
            float d1 = qdsh[ctx][ca[tt]] * 0.125f;
            float d2 = (sdim[tt] == 2) ? qdsh[ctx][cb[tt]] * 0.125f : -INFINITY;
            float m2 = fmaxf(fmaxf(d0, d1), d2);
            float e0 = expf(d0 - m2), e1 = expf(d1 - m2);
            float e2 = (sdim[tt] == 2) ? expf(d2 - m2) : 0.f;
            float inv = prob / (e0 + e1 + e2);
            pwx[tt] = e0 * inv; pwy[tt] = e1 * inv; pwz[tt] = e2 * inv;
        }
    }

    // coefficient collapse: y = c0*V0 + sum_s cs[s]*V[s+1]
    float c0[2]; float cs[2][8];
    #pragma unroll
    for (int tt = 0; tt < 2; ++tt) {
        c0[tt] = pwx[tt];
        #pragma unroll
        for (int s = 0; s < 8; ++s)
            cs[tt][s] = ((sl0c == s) ? pwy[tt] : 0.f) + ((sl1c == s) ? pwz[tt] : 0.f);
    }
    #pragma unroll
    for (int off = 32; off > 0; off >>= 1) {
        #pragma unroll
        for (int tt = 0; tt < 2; ++tt) {
            c0[tt] += __shfl_xor(c0[tt], off, 64);
            #pragma unroll
            for (int s = 0; s < 8; ++s)
                cs[tt][s] += __shfl_xor(cs[tt][s], off, 64);
        }
    }

    // y for both contexts (9 LDS b32 reads each)
    #pragma unroll
    for (int tt = 0; tt < 2; ++tt) {
        const int ctx = w * 2 + tt;
        const bool hasValid = (mx[tt] > -1e29f);
        const float v0 = VshW[ctx][0][lane];
        float y = v0;
        if (hasValid) {
            y = c0[tt] * v0;
            #pragma unroll
            for (int s = 0; s < 8; ++s)
                y += cs[tt][s] * VshW[ctx][s + 1][lane];
        }
        const int bb = bh / Hn, h = bh % Hn;
        yb[((size_t)(bb * Tn + ii[tt])) * Cn + h * HS + lane] = bf_rne(y);
    }
}

extern "C" void kernel_launch(void* const* d_in, const int* in_sizes, int n_in,
                              void* d_out, int out_size, void* d_ws, size_t ws_size,
                              hipStream_t stream) {
    const float* x      = (const float*)d_in[0];
    const float* W_attn = (const float*)d_in[1];
    const float* b_attn = (const float*)d_in[2];
    const float* W_proj = (const float*)d_in[3];
    const float* b_proj = (const float*)d_in[4];
    float* out = (float*)d_out;

    char* ws = (char*)d_ws;
    float* vh            = (float*)(ws);                          //  0        3 MB
    unsigned short* qcat = (unsigned short*)(ws + 3145728);       //  3 MB     9 MB
    unsigned short* kcat = (unsigned short*)(ws + 12582912);      // 12 MB     9 MB
    unsigned short* xcat = (unsigned short*)(ws + 22020096);      // 21 MB     4.5 MB (dead after qkv)
    unsigned short* Wcat = (unsigned short*)(ws + 26738688);      // 25.5 MB  10.125 MB (dead after qkv)
    float* S             = (float*)(ws + 26738688);               // overlays Wcat, 13.5 MB
    unsigned short* ybf  = xcat;                                  // overlays xcat after qkv
    unsigned short* Wpbf = (unsigned short*)(ws + 40894464);      // 39 MB     1.125 MB -> 40.1 MB total

    // 1) all conversions in one launch (xcat | Wcat | Wpbf)
    conv_all<<<dim3((NX + NW + NP + 255) / 256), 256, 0, stream>>>(
        x, W_attn, W_proj, xcat, Wcat, Wpbf);

    // 2) fused qkv: q/k 3-term (by<24) + v 1-term (by>=24)
    mfma_qkv<<<dim3(16, 36), 256, 0, stream>>>(xcat, Wcat, b_attn, qcat, kcat, vh);

    // 3) S = qcat @ kcat^T (K'=384, 6-term split), lower-triangle tiles, packed store
    mfma_sim<<<dim3(36, BH), 256, 0, stream>>>(qcat, kcat, S);

    // 4) dpp: two tokens per wave, coef-collapsed epilogue
    dpp_kernel<<<dim3(BH, Tn / 8), 256, 0, stream>>>(S, kcat, vh, ybf);

    // 5) out = y @ Wp^T + bias
    mfma_proj<<<dim3(16, 12), 256, 0, stream>>>(ybf, Wpbf, b_proj, out);
}

// Round 13
// 169.883 us; speedup vs baseline: 2.8853x; 2.8853x over previous
//
#include <hip/hip_runtime.h>
#include <math.h>

#define Bn 2
#define Hn 12
#define Tn 512
#define Cn 768
#define HS 64
#define BH 24
#define MTOP 8
#define NCOMB 36
#define NEGV -1e30f

#define NX (Bn * Tn * Cn)     // 786432
#define NW (3 * Cn * Cn)      // 1769472
#define NP (Cn * Cn)          // 589824

typedef __bf16 bf16x8 __attribute__((ext_vector_type(8)));
typedef float f32x4 __attribute__((ext_vector_type(4)));

__device__ __constant__ int C_SL0[NCOMB] = {
  0,1,2,3,4,5,6,7,
  0,0,0,0,0,0,0,
  1,1,1,1,1,1,
  2,2,2,2,2,
  3,3,3,3,
  4,4,4,
  5,5,
  6};
__device__ __constant__ int C_SL1[NCOMB] = {
  -1,-1,-1,-1,-1,-1,-1,-1,
  1,2,3,4,5,6,7,
  2,3,4,5,6,7,
  3,4,5,6,7,
  4,5,6,7,
  5,6,7,
  6,7,
  7};

__device__ __constant__ int PA[45] = {
  0,0,0,0,0,0,0,0,0,
  1,1,1,1,1,1,1,1,
  2,2,2,2,2,2,2,
  3,3,3,3,3,3,
  4,4,4,4,4,
  5,5,5,5,
  6,6,6,
  7,7,
  8};
__device__ __constant__ int PB[45] = {
  0,1,2,3,4,5,6,7,8,
  1,2,3,4,5,6,7,8,
  2,3,4,5,6,7,8,
  3,4,5,6,7,8,
  4,5,6,7,8,
  5,6,7,8,
  6,7,8,
  7,8,
  8};

// lower-triangle 8x8 tile enumeration (ti >= tj)
__device__ __constant__ int TI[36] = {
  0,1,1,2,2,2,3,3,3,3,4,4,4,4,4,5,5,5,5,5,5,6,6,6,6,6,6,6,7,7,7,7,7,7,7,7};
__device__ __constant__ int TJ[36] = {
  0,0,1,0,1,2,0,1,2,3,0,1,2,3,4,0,1,2,3,4,5,0,1,2,3,4,5,6,0,1,2,3,4,5,6,7};

__device__ __forceinline__ unsigned short bf_rne(float x) {
    unsigned u = __float_as_uint(x);
    return (unsigned short)((u + 0x7fff + ((u >> 16) & 1)) >> 16);
}
__device__ __forceinline__ float bf_f(unsigned short s) {
    return __uint_as_float(((unsigned)s) << 16);
}

// ---- fused conversions: xcat | Wcat | Wpbf in one launch -----------------------------
__global__ __launch_bounds__(256) void conv_all(const float* __restrict__ x,
                                                const float* __restrict__ Wa,
                                                const float* __restrict__ Wp,
                                                unsigned short* __restrict__ xcat,
                                                unsigned short* __restrict__ Wcat,
                                                unsigned short* __restrict__ Wpbf) {
    int idx = blockIdx.x * 256 + threadIdx.x;
    if (idx < NX) {
        int r = idx / Cn, c = idx - r * Cn;
        float v = x[idx];
        unsigned short h = bf_rne(v);
        unsigned short l = bf_rne(v - bf_f(h));
        size_t base = (size_t)r * 2304 + c;
        xcat[base] = h;            // [xhi | xhi | xlo]
        xcat[base + 768] = h;
        xcat[base + 1536] = l;
    } else if (idx < NX + NW) {
        int j = idx - NX;
        int r = j / Cn, c = j - r * Cn;
        float v = Wa[j];
        unsigned short h = bf_rne(v);
        unsigned short l = bf_rne(v - bf_f(h));
        size_t base = (size_t)r * 2304 + c;
        Wcat[base] = h;            // [Whi | Wlo | Whi]
        Wcat[base + 1536] = h;
        Wcat[base + 768] = l;
    } else if (idx < NX + NW + NP) {
        int j = idx - NX - NW;
        Wpbf[j] = bf_rne(Wp[j]);
    }
}

// ---- shared LDS-staged bf16 NT GEMM core, depth-2 prefetch (named reg sets) ----------
// Kst = row stride (elems); extent = NS*64 <= Kst. NS must be EVEN (36/12/6 all are).
// r12 lesson: dynamic-indexed register arrays (ra0[s&1]) get demoted to scratch ->
// 4x regression. This version manually unrolls by 2 with named sets A/B so both
// prefetch buffers stay in real VGPRs; each load has ~2 slabs of latency budget.
__device__ __forceinline__ void gemm_core(const unsigned short* __restrict__ Ag,
                                          const unsigned short* __restrict__ Bg,
                                          int Kst, int NS,
                                          unsigned short* Ab, unsigned short* Bb,
                                          f32x4 acc[2][2]) {
    const int tid = threadIdx.x;
    const int wv = tid >> 6, lane = tid & 63;
    const int r0 = tid >> 3;
    const int c8 = (tid & 7) * 8;
    const int m0w = (wv >> 1) * 32;
    const int n0w = (wv & 1) * 32;
    const int fr = lane & 15;
    const int fk = (lane >> 4) * 8;

    const unsigned short* pa0 = Ag + (size_t)r0 * Kst + c8;
    const unsigned short* pa1 = Ag + (size_t)(r0 + 32) * Kst + c8;
    const unsigned short* pb0 = Bg + (size_t)r0 * Kst + c8;
    const unsigned short* pb1 = Bg + (size_t)(r0 + 32) * Kst + c8;

    // set A holds even slabs, set B holds odd slabs
    bf16x8 raA0 = *(const bf16x8*)pa0;
    bf16x8 raA1 = *(const bf16x8*)pa1;
    bf16x8 rbA0 = *(const bf16x8*)pb0;
    bf16x8 rbA1 = *(const bf16x8*)pb1;
    bf16x8 raB0 = *(const bf16x8*)(pa0 + 64);
    bf16x8 raB1 = *(const bf16x8*)(pa1 + 64);
    bf16x8 rbB0 = *(const bf16x8*)(pb0 + 64);
    bf16x8 rbB1 = *(const bf16x8*)(pb1 + 64);

    const int sO = r0 * 72 + c8;

    auto compute = [&](int bufo) {
        #pragma unroll
        for (int ks = 0; ks < 2; ++ks) {
            bf16x8 af[2], bg[2];
            #pragma unroll
            for (int mi = 0; mi < 2; ++mi)
                af[mi] = *(const bf16x8*)(Ab + bufo + (m0w + 16 * mi + fr) * 72 + ks * 32 + fk);
            #pragma unroll
            for (int ni = 0; ni < 2; ++ni)
                bg[ni] = *(const bf16x8*)(Bb + bufo + (n0w + 16 * ni + fr) * 72 + ks * 32 + fk);
            #pragma unroll
            for (int mi = 0; mi < 2; ++mi)
                #pragma unroll
                for (int ni = 0; ni < 2; ++ni)
                    acc[mi][ni] = __builtin_amdgcn_mfma_f32_16x16x32_bf16(af[mi], bg[ni], acc[mi][ni], 0, 0, 0);
        }
    };

    for (int s = 0; s < NS; s += 2) {
        // even slab s: buffer 0 <- set A
        *(bf16x8*)(Ab + sO)           = raA0;
        *(bf16x8*)(Ab + sO + 32 * 72) = raA1;
        *(bf16x8*)(Bb + sO)           = rbA0;
        *(bf16x8*)(Bb + sO + 32 * 72) = rbA1;
        __syncthreads();
        if (s + 2 < NS) {            // prefetch slab s+2 into A (~2 slabs of budget)
            raA0 = *(const bf16x8*)(pa0 + (s + 2) * 64);
            raA1 = *(const bf16x8*)(pa1 + (s + 2) * 64);
            rbA0 = *(const bf16x8*)(pb0 + (s + 2) * 64);
            rbA1 = *(const bf16x8*)(pb1 + (s + 2) * 64);
        }
        compute(0);

        // odd slab s+1: buffer 1 <- set B
        *(bf16x8*)(Ab + 4608 + sO)           = raB0;
        *(bf16x8*)(Ab + 4608 + sO + 32 * 72) = raB1;
        *(bf16x8*)(Bb + 4608 + sO)           = rbB0;
        *(bf16x8*)(Bb + 4608 + sO + 32 * 72) = rbB1;
        __syncthreads();
        if (s + 3 < NS) {            // prefetch slab s+3 into B
            raB0 = *(const bf16x8*)(pa0 + (s + 3) * 64);
            raB1 = *(const bf16x8*)(pa1 + (s + 3) * 64);
            rbB0 = *(const bf16x8*)(pb0 + (s + 3) * 64);
            rbB1 = *(const bf16x8*)(pb1 + (s + 3) * 64);
        }
        compute(4608);
    }
}

// ---- qkv fused: by<24 -> q/k 3-term GEMM (K'=2304); by>=24 -> v 1-term (K=768) -------
__global__ __launch_bounds__(256) void mfma_qkv(const unsigned short* __restrict__ xcat,
                                                const unsigned short* __restrict__ Wcat,
                                                const float* __restrict__ bias,
                                                unsigned short* __restrict__ qcat,
                                                unsigned short* __restrict__ kcat,
                                                float* __restrict__ vh) {
    __shared__ unsigned short Ab[2 * 64 * 72];
    __shared__ unsigned short Bb[2 * 64 * 72];
    const int tm = blockIdx.x * 64;
    const int by = blockIdx.y;
    const int wv = threadIdx.x >> 6, lane = threadIdx.x & 63;
    const int kq = lane >> 4, r = lane & 15;
    f32x4 acc[2][2] = {};

    if (by < 24) {
        const int tn = by * 64;
        gemm_core(xcat + (size_t)tm * 2304, Wcat + (size_t)tn * 2304, 2304, 36, Ab, Bb, acc);
        const int part = tn / Cn;          // 0=q, 1=k
        #pragma unroll
        for (int mi = 0; mi < 2; ++mi) {
            #pragma unroll
            for (int ni = 0; ni < 2; ++ni) {
                #pragma unroll
                for (int rr = 0; rr < 4; ++rr) {
                    int mm = tm + (wv >> 1) * 32 + mi * 16 + kq * 4 + rr;
                    int nn = tn + (wv & 1) * 32 + ni * 16 + r;
                    float val = acc[mi][ni][rr] + bias[nn];
                    int bb = mm >> 9, t = mm & 511;
                    int c = nn - part * Cn;
                    int h = c >> 6, d = c & 63;
                    int bh = bb * Hn + h;
                    unsigned short s1 = bf_rne(val);
                    float r1 = val - bf_f(s1);
                    unsigned short s2 = bf_rne(r1);
                    unsigned short s3 = bf_rne(r1 - bf_f(s2));
                    size_t base = ((size_t)bh * Tn + t) * 384 + d;
                    if (part == 0) {   // qcat = [q1|q1|q2|q1|q3|q2]
                        qcat[base]       = s1;
                        qcat[base + 64]  = s1;
                        qcat[base + 192] = s1;
                        qcat[base + 128] = s2;
                        qcat[base + 320] = s2;
                        qcat[base + 256] = s3;
                    } else {           // kcat = [k1|k2|k1|k3|k1|k2]
                        kcat[base]       = s1;
                        kcat[base + 128] = s1;
                        kcat[base + 256] = s1;
                        kcat[base + 64]  = s2;
                        kcat[base + 320] = s2;
                        kcat[base + 192] = s3;
                    }
                }
            }
        }
    } else {
        // v: single-term bf16 (xhi @ Wvhi^T), K extent 768 within stride-2304 rows
        const int hvi = by - 24;           // head-col tile 0..11
        const int cv = hvi * 64;
        gemm_core(xcat + (size_t)tm * 2304,
                  Wcat + (size_t)(1536 + cv) * 2304, 2304, 12, Ab, Bb, acc);
        #pragma unroll
        for (int mi = 0; mi < 2; ++mi) {
            #pragma unroll
            for (int ni = 0; ni < 2; ++ni) {
                #pragma unroll
                for (int rr = 0; rr < 4; ++rr) {
                    int mm = tm + (wv >> 1) * 32 + mi * 16 + kq * 4 + rr;
                    int nloc = (wv & 1) * 32 + ni * 16 + r;      // 0..63 == d
                    float val = acc[mi][ni][rr] + bias[1536 + cv + nloc];
                    int bb = mm >> 9, t = mm & 511;
                    int bh = bb * Hn + hvi;
                    vh[((size_t)bh * Tn + t) * HS + nloc] = val;
                }
            }
        }
    }
}

// ---- sim: S = qcat @ kcat^T per bh (K'=384 = 6-term split), triangle tiles -----------
__global__ __launch_bounds__(256) void mfma_sim(const unsigned short* __restrict__ qcat,
                                                const unsigned short* __restrict__ kcat,
                                                float* __restrict__ S) {
    __shared__ unsigned short Ab[2 * 64 * 72];
    __shared__ unsigned short Bb[2 * 64 * 72];
    const int bh = blockIdx.y;
    const int ti = TI[blockIdx.x], tj = TJ[blockIdx.x];
    f32x4 acc[2][2] = {};
    gemm_core(qcat + ((size_t)bh * Tn + ti * 64) * 384,
              kcat + ((size_t)bh * Tn + tj * 64) * 384, 384, 6, Ab, Bb, acc);

    const int wv = threadIdx.x >> 6, lane = threadIdx.x & 63;
    const int kq = lane >> 4, r = lane & 15;
    float* Sp = S + (size_t)bh * 147456 + (size_t)(ti * (ti + 1) / 2 + tj) * 4096;
    #pragma unroll
    for (int mi = 0; mi < 2; ++mi)
        #pragma unroll
        for (int ni = 0; ni < 2; ++ni)
            #pragma unroll
            for (int rr = 0; rr < 4; ++rr) {
                int ml = (wv >> 1) * 32 + mi * 16 + kq * 4 + rr;
                int nl = (wv & 1) * 32 + ni * 16 + r;
                Sp[ml * 64 + nl] = acc[mi][ni][rr];
            }
}

// ---- proj: out = ybf @ Wpbf^T + bias (K=768) -----------------------------------------
__global__ __launch_bounds__(256) void mfma_proj(const unsigned short* __restrict__ Abf,
                                                 const unsigned short* __restrict__ Bbf,
                                                 const float* __restrict__ bias,
                                                 float* __restrict__ outp) {
    __shared__ unsigned short Ab[2 * 64 * 72];
    __shared__ unsigned short Bb[2 * 64 * 72];
    const int tm = blockIdx.x * 64;
    const int tn = blockIdx.y * 64;
    f32x4 acc[2][2] = {};
    gemm_core(Abf + (size_t)tm * Cn, Bbf + (size_t)tn * Cn, Cn, 12, Ab, Bb, acc);

    const int wv = threadIdx.x >> 6, lane = threadIdx.x & 63;
    const int kq = lane >> 4, r = lane & 15;
    #pragma unroll
    for (int mi = 0; mi < 2; ++mi)
        #pragma unroll
        for (int ni = 0; ni < 2; ++ni)
            #pragma unroll
            for (int rr = 0; rr < 4; ++rr) {
                int mm = tm + (wv >> 1) * 32 + mi * 16 + kq * 4 + rr;
                int nn = tn + (wv & 1) * 32 + ni * 16 + r;
                outp[(size_t)mm * Cn + nn] = acc[mi][ni][rr] + bias[nn];
            }
}

// ---- DPP selection: TWO tokens per wave; coef-collapsed epilogue ---------------------
__global__ __launch_bounds__(256) void dpp_kernel(const float* __restrict__ S,
                                                  const unsigned short* __restrict__ kcat,
                                                  const float* __restrict__ vh,
                                                  unsigned short* __restrict__ yb) {
    const int bh = blockIdx.x;
    const int w = threadIdx.x >> 6;
    const int lane = threadIdx.x & 63;
    const int ibase = blockIdx.y * 8 + w * 2;

    __shared__ float KshW[8][9][68];   // 19584 B
    __shared__ float VshW[8][9][65];   // 18720 B
    __shared__ float Gsh[8][81];       //  2592 B
    __shared__ float qdsh[8][12];      //   384 B  -> 41280 B total
    const float* Sbh = S + (size_t)bh * 147456;
    const unsigned short* kc = kcat + (size_t)bh * Tn * 384;
    const float* vbase = vh + (size_t)bh * Tn * HS;

    int ii[2], tib[2];
    float sv[2][8];
    #pragma unroll
    for (int tt = 0; tt < 2; ++tt) {
        const int i = ibase + tt;
        ii[tt] = i;
        const int t8 = i >> 6;
        tib[tt] = t8;
        const int tribase = t8 * (t8 + 1) / 2;
        const int rloc = (i & 63) * 64;
        #pragma unroll
        for (int rr = 0; rr < 8; ++rr) {
            sv[tt][rr] = -INFINITY;
            if (rr <= t8) {
                int j = rr * 64 + lane;
                float s = Sbh[(size_t)(tribase + rr) * 4096 + rloc + lane];
                sv[tt][rr] = (j <= i) ? s : -INFINITY;
            }
        }
    }

    // qd0 = sim[i][i]
    float qd0[2] = {0.f, 0.f};
    #pragma unroll
    for (int c = 0; c < 8; ++c)
        #pragma unroll
        for (int tt = 0; tt < 2; ++tt) {
            float t = __shfl(sv[tt][c], ii[tt] & 63, 64);
            if (c == tib[tt]) qd0[tt] = t;
        }

    // top-8: 8 passes, two interleaved butterflies (value desc, tie -> lower index)
    float topv[2][8]; int topi[2][8];
    #pragma unroll
    for (int p = 0; p < MTOP; ++p) {
        float bv[2]; int bi[2];
        #pragma unroll
        for (int tt = 0; tt < 2; ++tt) {
            bv[tt] = -INFINITY; bi[tt] = 0x7fffffff;
            #pragma unroll
            for (int r = 0; r < 8; ++r) {
                int j = r * 64 + lane;
                float v = sv[tt][r];
                if (v > bv[tt] || (v == bv[tt] && j < bi[tt])) { bv[tt] = v; bi[tt] = j; }
            }
        }
        #pragma unroll
        for (int off = 32; off > 0; off >>= 1)
            #pragma unroll
            for (int tt = 0; tt < 2; ++tt) {
                float ov = __shfl_xor(bv[tt], off, 64);
                int   oi = __shfl_xor(bi[tt], off, 64);
                if (ov > bv[tt] || (ov == bv[tt] && oi < bi[tt])) { bv[tt] = ov; bi[tt] = oi; }
            }
        #pragma unroll
        for (int tt = 0; tt < 2; ++tt) {
            topv[tt][p] = bv[tt]; topi[tt][p] = bi[tt];
            const int rs = bi[tt] >> 6, ls = bi[tt] & 63;
            #pragma unroll
            for (int r = 0; r < 8; ++r)
                if (r == rs && lane == ls) sv[tt][r] = -INFINITY;
        }
    }

    // stage K/V rows for both contexts
    #pragma unroll
    for (int tt = 0; tt < 2; ++tt) {
        const int ctx = w * 2 + tt;
        #pragma unroll
        for (int a = 0; a < 9; ++a) {
            int t = (a == 0) ? ii[tt] : topi[tt][a - 1];
            size_t kb = (size_t)t * 384 + lane;
            KshW[ctx][a][lane] = bf_f(kc[kb]) + bf_f(kc[kb + 64]) + bf_f(kc[kb + 192]);
            VshW[ctx][a][lane] = vbase[(size_t)t * HS + lane];
        }
        if (lane < 9) {
            float val = qd0[tt];
            #pragma unroll
            for (int p = 0; p < 8; ++p) if (lane == p + 1) val = topv[tt][p];
            qdsh[ctx][lane] = val;
        }
    }

    // gram for both contexts
    if (lane < 45) {
        const int a = PA[lane], b = PB[lane];
        #pragma unroll
        for (int tt = 0; tt < 2; ++tt) {
            const int ctx = w * 2 + tt;
            const float4* rka = (const float4*)&KshW[ctx][a][0];
            const float4* rkb = (const float4*)&KshW[ctx][b][0];
            float acc = 0.f;
            #pragma unroll
            for (int t = 0; t < 16; ++t) {
                float4 fa = rka[t], fb = rkb[t];
                acc += fa.x * fb.x; acc += fa.y * fb.y;
                acc += fa.z * fb.z; acc += fa.w * fb.w;
            }
            Gsh[ctx][a * 9 + b] = acc;
            Gsh[ctx][b * 9 + a] = acc;
        }
    }

    // combos (lanes 0..35)
    const int sl0c = (lane < NCOMB) ? C_SL0[lane] : -1;
    const int sl1c = (lane < NCOMB) ? C_SL1[lane] : -1;
    float score[2]; int ca[2], cb[2], sdim[2];
    #pragma unroll
    for (int tt = 0; tt < 2; ++tt) {
        const int ctx = w * 2 + tt;
        const int i = ii[tt];
        const int n_cand = (i + 1 < MTOP) ? (i + 1) : MTOP;
        int vmask = 0;
        #pragma unroll
        for (int s = 0; s < MTOP; ++s)
            if (s < n_cand && topi[tt][s] != i) vmask |= (1 << s);

        score[tt] = -INFINITY; ca[tt] = 0; cb[tt] = 0; sdim[tt] = 1;
        if (lane < NCOMB) {
            sdim[tt] = (sl1c < 0) ? 1 : 2;
            ca[tt] = sl0c + 1;
            cb[tt] = (sl1c < 0) ? 0 : sl1c + 1;
            bool valid = ((vmask >> sl0c) & 1);
            if (sdim[tt] == 2) valid = valid && ((vmask >> sl1c) & 1);
            float G00 = Gsh[ctx][0];
            float Gaa = Gsh[ctx][ca[tt] * 9 + ca[tt]];
            float G0a = Gsh[ctx][ca[tt]];
            float det;
            if (sdim[tt] == 1) {
                det = G00 * Gaa - G0a * G0a;
            } else {
                float G0b = Gsh[ctx][cb[tt]];
                float Gab = Gsh[ctx][ca[tt] * 9 + cb[tt]];
                float Gbb = Gsh[ctx][cb[tt] * 9 + cb[tt]];
                det = G00 * (Gaa * Gbb - Gab * Gab)
                    - G0a * (G0a * Gbb - Gab * G0b)
                    + G0b * (G0a * Gab - Gaa * G0b);
            }
            score[tt] = valid ? (logf(det + 1e-6f) / (float)(sdim[tt] + 1)) : NEGV;
        }
    }

    float mx[2] = {score[0], score[1]};
    #pragma unroll
    for (int off = 32; off > 0; off >>= 1)
        #pragma unroll
        for (int tt = 0; tt < 2; ++tt)
            mx[tt] = fmaxf(mx[tt], __shfl_xor(mx[tt], off, 64));
    float ee[2];
    #pragma unroll
    for (int tt = 0; tt < 2; ++tt)
        ee[tt] = (lane < NCOMB) ? expf(score[tt] - mx[tt]) : 0.f;
    float sum[2] = {ee[0], ee[1]};
    #pragma unroll
    for (int off = 32; off > 0; off >>= 1)
        #pragma unroll
        for (int tt = 0; tt < 2; ++tt)
            sum[tt] += __shfl_xor(sum[tt], off, 64);

    // per-lane prob-folded attention weights
    float pwx[2] = {0.f, 0.f}, pwy[2] = {0.f, 0.f}, pwz[2] = {0.f, 0.f};
    #pragma unroll
    for (int tt = 0; tt < 2; ++tt) {
        const int ctx = w * 2 + tt;
        if (lane < NCOMB) {
            float prob = ee[tt] / sum[tt];
            float d0 = qdsh[ctx][0]      * 0.125f;
            float d1 = qdsh[ctx][ca[tt]] * 0.125f;
            float d2 = (sdim[tt] == 2) ? qdsh[ctx][cb[tt]] * 0.125f : -INFINITY;
            float m2 = fmaxf(fmaxf(d0, d1), d2);
            float e0 = expf(d0 - m2), e1 = expf(d1 - m2);
            float e2 = (sdim[tt] == 2) ? expf(d2 - m2) : 0.f;
            float inv = prob / (e0 + e1 + e2);
            pwx[tt] = e0 * inv; pwy[tt] = e1 * inv; pwz[tt] = e2 * inv;
        }
    }

    // coefficient collapse: y = c0*V0 + sum_s cs[s]*V[s+1]
    float c0[2]; float cs[2][8];
    #pragma unroll
    for (int tt = 0; tt < 2; ++tt) {
        c0[tt] = pwx[tt];
        #pragma unroll
        for (int s = 0; s < 8; ++s)
            cs[tt][s] = ((sl0c == s) ? pwy[tt] : 0.f) + ((sl1c == s) ? pwz[tt] : 0.f);
    }
    #pragma unroll
    for (int off = 32; off > 0; off >>= 1) {
        #pragma unroll
        for (int tt = 0; tt < 2; ++tt) {
            c0[tt] += __shfl_xor(c0[tt], off, 64);
            #pragma unroll
            for (int s = 0; s < 8; ++s)
                cs[tt][s] += __shfl_xor(cs[tt][s], off, 64);
        }
    }

    // y for both contexts (9 LDS b32 reads each)
    #pragma unroll
    for (int tt = 0; tt < 2; ++tt) {
        const int ctx = w * 2 + tt;
        const bool hasValid = (mx[tt] > -1e29f);
        const float v0 = VshW[ctx][0][lane];
        float y = v0;
        if (hasValid) {
            y = c0[tt] * v0;
            #pragma unroll
            for (int s = 0; s < 8; ++s)
                y += cs[tt][s] * VshW[ctx][s + 1][lane];
        }
        const int bb = bh / Hn, h = bh % Hn;
        yb[((size_t)(bb * Tn + ii[tt])) * Cn + h * HS + lane] = bf_rne(y);
    }
}

extern "C" void kernel_launch(void* const* d_in, const int* in_sizes, int n_in,
                              void* d_out, int out_size, void* d_ws, size_t ws_size,
                              hipStream_t stream) {
    const float* x      = (const float*)d_in[0];
    const float* W_attn = (const float*)d_in[1];
    const float* b_attn = (const float*)d_in[2];
    const float* W_proj = (const float*)d_in[3];
    const float* b_proj = (const float*)d_in[4];
    float* out = (float*)d_out;

    char* ws = (char*)d_ws;
    float* vh            = (float*)(ws);                          //  0        3 MB
    unsigned short* qcat = (unsigned short*)(ws + 3145728);       //  3 MB     9 MB
    unsigned short* kcat = (unsigned short*)(ws + 12582912);      // 12 MB     9 MB
    unsigned short* xcat = (unsigned short*)(ws + 22020096);      // 21 MB     4.5 MB (dead after qkv)
    unsigned short* Wcat = (unsigned short*)(ws + 26738688);      // 25.5 MB  10.125 MB (dead after qkv)
    float* S             = (float*)(ws + 26738688);               // overlays Wcat, 13.5 MB
    unsigned short* ybf  = xcat;                                  // overlays xcat after qkv
    unsigned short* Wpbf = (unsigned short*)(ws + 40894464);      // 39 MB     1.125 MB -> 40.1 MB total

    // 1) all conversions in one launch (xcat | Wcat | Wpbf)
    conv_all<<<dim3((NX + NW + NP + 255) / 256), 256, 0, stream>>>(
        x, W_attn, W_proj, xcat, Wcat, Wpbf);

    // 2) fused qkv: q/k 3-term (by<24) + v 1-term (by>=24)
    mfma_qkv<<<dim3(16, 36), 256, 0, stream>>>(xcat, Wcat, b_attn, qcat, kcat, vh);

    // 3) S = qcat @ kcat^T (K'=384, 6-term split), lower-triangle tiles, packed store
    mfma_sim<<<dim3(36, BH), 256, 0, stream>>>(qcat, kcat, S);

    // 4) dpp: two tokens per wave, coef-collapsed epilogue
    dpp_kernel<<<dim3(BH, Tn / 8), 256, 0, stream>>>(S, kcat, vh, ybf);

    // 5) out = y @ Wp^T + bias
    mfma_proj<<<dim3(16, 12), 256, 0, stream>>>(ybf, Wpbf, b_proj, out);
}

// Round 14
// 169.045 us; speedup vs baseline: 2.8996x; 1.0050x over previous
//
#include <hip/hip_runtime.h>
#include <math.h>

#define Bn 2
#define Hn 12
#define Tn 512
#define Cn 768
#define HS 64
#define BH 24
#define MTOP 8
#define NCOMB 36
#define NEGV -1e30f

#define NX (Bn * Tn * Cn)     // 786432
#define NW (3 * Cn * Cn)      // 1769472
#define NP (Cn * Cn)          // 589824

typedef __bf16 bf16x8 __attribute__((ext_vector_type(8)));
typedef float f32x4 __attribute__((ext_vector_type(4)));

__device__ __constant__ int C_SL0[NCOMB] = {
  0,1,2,3,4,5,6,7,
  0,0,0,0,0,0,0,
  1,1,1,1,1,1,
  2,2,2,2,2,
  3,3,3,3,
  4,4,4,
  5,5,
  6};
__device__ __constant__ int C_SL1[NCOMB] = {
  -1,-1,-1,-1,-1,-1,-1,-1,
  1,2,3,4,5,6,7,
  2,3,4,5,6,7,
  3,4,5,6,7,
  4,5,6,7,
  5,6,7,
  6,7,
  7};

__device__ __constant__ int PA[45] = {
  0,0,0,0,0,0,0,0,0,
  1,1,1,1,1,1,1,1,
  2,2,2,2,2,2,2,
  3,3,3,3,3,3,
  4,4,4,4,4,
  5,5,5,5,
  6,6,6,
  7,7,
  8};
__device__ __constant__ int PB[45] = {
  0,1,2,3,4,5,6,7,8,
  1,2,3,4,5,6,7,8,
  2,3,4,5,6,7,8,
  3,4,5,6,7,8,
  4,5,6,7,8,
  5,6,7,8,
  6,7,8,
  7,8,
  8};

// lower-triangle 8x8 tile enumeration (ti >= tj)
__device__ __constant__ int TI[36] = {
  0,1,1,2,2,2,3,3,3,3,4,4,4,4,4,5,5,5,5,5,5,6,6,6,6,6,6,6,7,7,7,7,7,7,7,7};
__device__ __constant__ int TJ[36] = {
  0,0,1,0,1,2,0,1,2,3,0,1,2,3,4,0,1,2,3,4,5,0,1,2,3,4,5,6,0,1,2,3,4,5,6,7};

__device__ __forceinline__ unsigned short bf_rne(float x) {
    unsigned u = __float_as_uint(x);
    return (unsigned short)((u + 0x7fff + ((u >> 16) & 1)) >> 16);
}
__device__ __forceinline__ float bf_f(unsigned short s) {
    return __uint_as_float(((unsigned)s) << 16);
}

// ---- fused conversions: xcat | Wcat | Wpbf in one launch -----------------------------
__global__ __launch_bounds__(256) void conv_all(const float* __restrict__ x,
                                                const float* __restrict__ Wa,
                                                const float* __restrict__ Wp,
                                                unsigned short* __restrict__ xcat,
                                                unsigned short* __restrict__ Wcat,
                                                unsigned short* __restrict__ Wpbf) {
    int idx = blockIdx.x * 256 + threadIdx.x;
    if (idx < NX) {
        int r = idx / Cn, c = idx - r * Cn;
        float v = x[idx];
        unsigned short h = bf_rne(v);
        unsigned short l = bf_rne(v - bf_f(h));
        size_t base = (size_t)r * 2304 + c;
        xcat[base] = h;            // [xhi | xhi | xlo]
        xcat[base + 768] = h;
        xcat[base + 1536] = l;
    } else if (idx < NX + NW) {
        int j = idx - NX;
        int r = j / Cn, c = j - r * Cn;
        float v = Wa[j];
        unsigned short h = bf_rne(v);
        unsigned short l = bf_rne(v - bf_f(h));
        size_t base = (size_t)r * 2304 + c;
        Wcat[base] = h;            // [Whi | Wlo | Whi]
        Wcat[base + 1536] = h;
        Wcat[base + 768] = l;
    } else if (idx < NX + NW + NP) {
        int j = idx - NX - NW;
        Wpbf[j] = bf_rne(Wp[j]);
    }
}

// ---- shared LDS-staged bf16 NT GEMM core, depth-2 prefetch (named reg sets) ----------
// Kst = row stride (elems); extent = NS*64 <= Kst. NS must be EVEN (36/12/6 all are).
// r12 lesson: dynamic-indexed register arrays get demoted to scratch -> 4x regression.
// Named sets A/B keep both prefetch buffers in real VGPRs (r13: verified win).
__device__ __forceinline__ void gemm_core(const unsigned short* __restrict__ Ag,
                                          const unsigned short* __restrict__ Bg,
                                          int Kst, int NS,
                                          unsigned short* Ab, unsigned short* Bb,
                                          f32x4 acc[2][2]) {
    const int tid = threadIdx.x;
    const int wv = tid >> 6, lane = tid & 63;
    const int r0 = tid >> 3;
    const int c8 = (tid & 7) * 8;
    const int m0w = (wv >> 1) * 32;
    const int n0w = (wv & 1) * 32;
    const int fr = lane & 15;
    const int fk = (lane >> 4) * 8;

    const unsigned short* pa0 = Ag + (size_t)r0 * Kst + c8;
    const unsigned short* pa1 = Ag + (size_t)(r0 + 32) * Kst + c8;
    const unsigned short* pb0 = Bg + (size_t)r0 * Kst + c8;
    const unsigned short* pb1 = Bg + (size_t)(r0 + 32) * Kst + c8;

    bf16x8 raA0 = *(const bf16x8*)pa0;
    bf16x8 raA1 = *(const bf16x8*)pa1;
    bf16x8 rbA0 = *(const bf16x8*)pb0;
    bf16x8 rbA1 = *(const bf16x8*)pb1;
    bf16x8 raB0 = *(const bf16x8*)(pa0 + 64);
    bf16x8 raB1 = *(const bf16x8*)(pa1 + 64);
    bf16x8 rbB0 = *(const bf16x8*)(pb0 + 64);
    bf16x8 rbB1 = *(const bf16x8*)(pb1 + 64);

    const int sO = r0 * 72 + c8;

    auto compute = [&](int bufo) {
        #pragma unroll
        for (int ks = 0; ks < 2; ++ks) {
            bf16x8 af[2], bg[2];
            #pragma unroll
            for (int mi = 0; mi < 2; ++mi)
                af[mi] = *(const bf16x8*)(Ab + bufo + (m0w + 16 * mi + fr) * 72 + ks * 32 + fk);
            #pragma unroll
            for (int ni = 0; ni < 2; ++ni)
                bg[ni] = *(const bf16x8*)(Bb + bufo + (n0w + 16 * ni + fr) * 72 + ks * 32 + fk);
            #pragma unroll
            for (int mi = 0; mi < 2; ++mi)
                #pragma unroll
                for (int ni = 0; ni < 2; ++ni)
                    acc[mi][ni] = __builtin_amdgcn_mfma_f32_16x16x32_bf16(af[mi], bg[ni], acc[mi][ni], 0, 0, 0);
        }
    };

    for (int s = 0; s < NS; s += 2) {
        *(bf16x8*)(Ab + sO)           = raA0;
        *(bf16x8*)(Ab + sO + 32 * 72) = raA1;
        *(bf16x8*)(Bb + sO)           = rbA0;
        *(bf16x8*)(Bb + sO + 32 * 72) = rbA1;
        __syncthreads();
        if (s + 2 < NS) {
            raA0 = *(const bf16x8*)(pa0 + (s + 2) * 64);
            raA1 = *(const bf16x8*)(pa1 + (s + 2) * 64);
            rbA0 = *(const bf16x8*)(pb0 + (s + 2) * 64);
            rbA1 = *(const bf16x8*)(pb1 + (s + 2) * 64);
        }
        compute(0);

        *(bf16x8*)(Ab + 4608 + sO)           = raB0;
        *(bf16x8*)(Ab + 4608 + sO + 32 * 72) = raB1;
        *(bf16x8*)(Bb + 4608 + sO)           = rbB0;
        *(bf16x8*)(Bb + 4608 + sO + 32 * 72) = rbB1;
        __syncthreads();
        if (s + 3 < NS) {
            raB0 = *(const bf16x8*)(pa0 + (s + 3) * 64);
            raB1 = *(const bf16x8*)(pa1 + (s + 3) * 64);
            rbB0 = *(const bf16x8*)(pb0 + (s + 3) * 64);
            rbB1 = *(const bf16x8*)(pb1 + (s + 3) * 64);
        }
        compute(4608);
    }
}

// ---- qkv fused: by<24 -> q/k 3-term GEMM (K'=2304); by>=24 -> v 1-term (K=768) -------
__global__ __launch_bounds__(256) void mfma_qkv(const unsigned short* __restrict__ xcat,
                                                const unsigned short* __restrict__ Wcat,
                                                const float* __restrict__ bias,
                                                unsigned short* __restrict__ qcat,
                                                unsigned short* __restrict__ kcat,
                                                float* __restrict__ vh) {
    __shared__ unsigned short Ab[2 * 64 * 72];
    __shared__ unsigned short Bb[2 * 64 * 72];
    const int tm = blockIdx.x * 64;
    const int by = blockIdx.y;
    const int wv = threadIdx.x >> 6, lane = threadIdx.x & 63;
    const int kq = lane >> 4, r = lane & 15;
    f32x4 acc[2][2] = {};

    if (by < 24) {
        const int tn = by * 64;
        gemm_core(xcat + (size_t)tm * 2304, Wcat + (size_t)tn * 2304, 2304, 36, Ab, Bb, acc);
        const int part = tn / Cn;          // 0=q, 1=k
        #pragma unroll
        for (int mi = 0; mi < 2; ++mi) {
            #pragma unroll
            for (int ni = 0; ni < 2; ++ni) {
                #pragma unroll
                for (int rr = 0; rr < 4; ++rr) {
                    int mm = tm + (wv >> 1) * 32 + mi * 16 + kq * 4 + rr;
                    int nn = tn + (wv & 1) * 32 + ni * 16 + r;
                    float val = acc[mi][ni][rr] + bias[nn];
                    int bb = mm >> 9, t = mm & 511;
                    int c = nn - part * Cn;
                    int h = c >> 6, d = c & 63;
                    int bh = bb * Hn + h;
                    unsigned short s1 = bf_rne(val);
                    float r1 = val - bf_f(s1);
                    unsigned short s2 = bf_rne(r1);
                    unsigned short s3 = bf_rne(r1 - bf_f(s2));
                    size_t base = ((size_t)bh * Tn + t) * 384 + d;
                    if (part == 0) {   // qcat = [q1|q1|q2|q1|q3|q2]
                        qcat[base]       = s1;
                        qcat[base + 64]  = s1;
                        qcat[base + 192] = s1;
                        qcat[base + 128] = s2;
                        qcat[base + 320] = s2;
                        qcat[base + 256] = s3;
                    } else {           // kcat = [k1|k2|k1|k3|k1|k2]
                        kcat[base]       = s1;
                        kcat[base + 128] = s1;
                        kcat[base + 256] = s1;
                        kcat[base + 64]  = s2;
                        kcat[base + 320] = s2;
                        kcat[base + 192] = s3;
                    }
                }
            }
        }
    } else {
        // v: single-term bf16 (xhi @ Wvhi^T), K extent 768 within stride-2304 rows
        const int hvi = by - 24;           // head-col tile 0..11
        const int cv = hvi * 64;
        gemm_core(xcat + (size_t)tm * 2304,
                  Wcat + (size_t)(1536 + cv) * 2304, 2304, 12, Ab, Bb, acc);
        #pragma unroll
        for (int mi = 0; mi < 2; ++mi) {
            #pragma unroll
            for (int ni = 0; ni < 2; ++ni) {
                #pragma unroll
                for (int rr = 0; rr < 4; ++rr) {
                    int mm = tm + (wv >> 1) * 32 + mi * 16 + kq * 4 + rr;
                    int nloc = (wv & 1) * 32 + ni * 16 + r;      // 0..63 == d
                    float val = acc[mi][ni][rr] + bias[1536 + cv + nloc];
                    int bb = mm >> 9, t = mm & 511;
                    int bh = bb * Hn + hvi;
                    vh[((size_t)bh * Tn + t) * HS + nloc] = val;
                }
            }
        }
    }
}

// ---- sim: S = qcat @ kcat^T per bh (K'=384 = 6-term split), triangle tiles -----------
__global__ __launch_bounds__(256) void mfma_sim(const unsigned short* __restrict__ qcat,
                                                const unsigned short* __restrict__ kcat,
                                                float* __restrict__ S) {
    __shared__ unsigned short Ab[2 * 64 * 72];
    __shared__ unsigned short Bb[2 * 64 * 72];
    const int bh = blockIdx.y;
    const int ti = TI[blockIdx.x], tj = TJ[blockIdx.x];
    f32x4 acc[2][2] = {};
    gemm_core(qcat + ((size_t)bh * Tn + ti * 64) * 384,
              kcat + ((size_t)bh * Tn + tj * 64) * 384, 384, 6, Ab, Bb, acc);

    const int wv = threadIdx.x >> 6, lane = threadIdx.x & 63;
    const int kq = lane >> 4, r = lane & 15;
    float* Sp = S + (size_t)bh * 147456 + (size_t)(ti * (ti + 1) / 2 + tj) * 4096;
    #pragma unroll
    for (int mi = 0; mi < 2; ++mi)
        #pragma unroll
        for (int ni = 0; ni < 2; ++ni)
            #pragma unroll
            for (int rr = 0; rr < 4; ++rr) {
                int ml = (wv >> 1) * 32 + mi * 16 + kq * 4 + rr;
                int nl = (wv & 1) * 32 + ni * 16 + r;
                Sp[ml * 64 + nl] = acc[mi][ni][rr];
            }
}

// ---- proj: out = ybf @ Wpbf^T + bias (K=768) -----------------------------------------
__global__ __launch_bounds__(256) void mfma_proj(const unsigned short* __restrict__ Abf,
                                                 const unsigned short* __restrict__ Bbf,
                                                 const float* __restrict__ bias,
                                                 float* __restrict__ outp) {
    __shared__ unsigned short Ab[2 * 64 * 72];
    __shared__ unsigned short Bb[2 * 64 * 72];
    const int tm = blockIdx.x * 64;
    const int tn = blockIdx.y * 64;
    f32x4 acc[2][2] = {};
    gemm_core(Abf + (size_t)tm * Cn, Bbf + (size_t)tn * Cn, Cn, 12, Ab, Bb, acc);

    const int wv = threadIdx.x >> 6, lane = threadIdx.x & 63;
    const int kq = lane >> 4, r = lane & 15;
    #pragma unroll
    for (int mi = 0; mi < 2; ++mi)
        #pragma unroll
        for (int ni = 0; ni < 2; ++ni)
            #pragma unroll
            for (int rr = 0; rr < 4; ++rr) {
                int mm = tm + (wv >> 1) * 32 + mi * 16 + kq * 4 + rr;
                int nn = tn + (wv & 1) * 32 + ni * 16 + r;
                outp[(size_t)mm * Cn + nn] = acc[mi][ni][rr] + bias[nn];
            }
}

// compare-exchange for u64 keys, descending (larger key to lower index)
#define CE64(arr, ia, ib) { \
    unsigned long long _a = arr[ia], _b = arr[ib]; \
    bool _sw = _a < _b; \
    arr[ia] = _sw ? _b : _a; arr[ib] = _sw ? _a : _b; }

// ---- DPP selection: TWO tokens per wave; merge-based top-8 (6-stage chain) -----------
// Top-8 via packed u64 keys (ordered_f32<<32 | ~idx): per-lane Batcher sort-8, then
// 6 butterfly stages of bitonic top-8 merge. Exact (v desc, idx asc) semantics; the
// 48-dependent-shuffle chain of the old 8-pass argmax becomes 6 dependent stages.
__global__ __launch_bounds__(256) void dpp_kernel(const float* __restrict__ S,
                                                  const unsigned short* __restrict__ kcat,
                                                  const float* __restrict__ vh,
                                                  unsigned short* __restrict__ yb) {
    const int bh = blockIdx.x;
    const int w = threadIdx.x >> 6;
    const int lane = threadIdx.x & 63;
    const int ibase = blockIdx.y * 8 + w * 2;

    __shared__ float KshW[8][9][68];   // 19584 B
    __shared__ float VshW[8][9][65];   // 18720 B
    __shared__ float Gsh[8][81];       //  2592 B
    __shared__ float qdsh[8][12];      //   384 B  -> 41280 B total
    const float* Sbh = S + (size_t)bh * 147456;
    const unsigned short* kc = kcat + (size_t)bh * Tn * 384;
    const float* vbase = vh + (size_t)bh * Tn * HS;

    int ii[2], tib[2];
    float sv[2][8];
    #pragma unroll
    for (int tt = 0; tt < 2; ++tt) {
        const int i = ibase + tt;
        ii[tt] = i;
        const int t8 = i >> 6;
        tib[tt] = t8;
        const int tribase = t8 * (t8 + 1) / 2;
        const int rloc = (i & 63) * 64;
        #pragma unroll
        for (int rr = 0; rr < 8; ++rr) {
            sv[tt][rr] = -INFINITY;
            if (rr <= t8) {
                int j = rr * 64 + lane;
                float s = Sbh[(size_t)(tribase + rr) * 4096 + rloc + lane];
                sv[tt][rr] = (j <= i) ? s : -INFINITY;
            }
        }
    }

    // qd0 = sim[i][i]
    float qd0[2] = {0.f, 0.f};
    #pragma unroll
    for (int c = 0; c < 8; ++c)
        #pragma unroll
        for (int tt = 0; tt < 2; ++tt) {
            float t = __shfl(sv[tt][c], ii[tt] & 63, 64);
            if (c == tib[tt]) qd0[tt] = t;
        }

    // ---- top-8 via sorted-key merge --------------------------------------------------
    // key = ordered(v) << 32 | ~j  (all keys distinct; desc key order == (v desc, j asc))
    unsigned long long key[2][8];
    #pragma unroll
    for (int tt = 0; tt < 2; ++tt)
        #pragma unroll
        for (int r = 0; r < 8; ++r) {
            unsigned u = __float_as_uint(sv[tt][r]);
            unsigned ou = u ^ ((unsigned)((int)u >> 31) | 0x80000000u);
            unsigned j = (unsigned)(r * 64 + lane);
            key[tt][r] = ((unsigned long long)ou << 32) | (unsigned)(~j);
        }

    // per-lane Batcher odd-even mergesort 8 (descending)
    #pragma unroll
    for (int tt = 0; tt < 2; ++tt) {
        CE64(key[tt],0,1) CE64(key[tt],2,3) CE64(key[tt],4,5) CE64(key[tt],6,7)
        CE64(key[tt],0,2) CE64(key[tt],1,3) CE64(key[tt],4,6) CE64(key[tt],5,7)
        CE64(key[tt],1,2) CE64(key[tt],5,6)
        CE64(key[tt],0,4) CE64(key[tt],1,5) CE64(key[tt],2,6) CE64(key[tt],3,7)
        CE64(key[tt],2,4) CE64(key[tt],3,5)
        CE64(key[tt],1,2) CE64(key[tt],3,4) CE64(key[tt],5,6)
    }

    // 6 butterfly merge stages: keep sorted top-8 of self U partner
    #pragma unroll
    for (int st = 0; st < 6; ++st) {
        const int off = 1 << st;
        #pragma unroll
        for (int tt = 0; tt < 2; ++tt) {
            unsigned long long pk[8];
            #pragma unroll
            for (int r = 0; r < 8; ++r)
                pk[r] = __shfl_xor(key[tt][r], off, 64);
            unsigned long long t[8];
            #pragma unroll
            for (int r = 0; r < 8; ++r) {
                unsigned long long b = pk[7 - r];
                t[r] = (key[tt][r] > b) ? key[tt][r] : b;   // bitonic half-cleaner
            }
            // bitonic sort-8 descending (dist 4, 2, 1)
            CE64(t,0,4) CE64(t,1,5) CE64(t,2,6) CE64(t,3,7)
            CE64(t,0,2) CE64(t,1,3) CE64(t,4,6) CE64(t,5,7)
            CE64(t,0,1) CE64(t,2,3) CE64(t,4,5) CE64(t,6,7)
            #pragma unroll
            for (int r = 0; r < 8; ++r) key[tt][r] = t[r];
        }
    }

    // unpack
    float topv[2][8]; int topi[2][8];
    #pragma unroll
    for (int tt = 0; tt < 2; ++tt)
        #pragma unroll
        for (int p = 0; p < 8; ++p) {
            unsigned long long kk = key[tt][p];
            unsigned ou = (unsigned)(kk >> 32);
            unsigned u = ou ^ ((ou & 0x80000000u) ? 0x80000000u : 0xFFFFFFFFu);
            topv[tt][p] = __uint_as_float(u);
            topi[tt][p] = (int)(~(unsigned)(kk & 0xFFFFFFFFull));
        }

    // stage K/V rows for both contexts
    #pragma unroll
    for (int tt = 0; tt < 2; ++tt) {
        const int ctx = w * 2 + tt;
        #pragma unroll
        for (int a = 0; a < 9; ++a) {
            int t = (a == 0) ? ii[tt] : topi[tt][a - 1];
            size_t kb = (size_t)t * 384 + lane;
            KshW[ctx][a][lane] = bf_f(kc[kb]) + bf_f(kc[kb + 64]) + bf_f(kc[kb + 192]);
            VshW[ctx][a][lane] = vbase[(size_t)t * HS + lane];
        }
        if (lane < 9) {
            float val = qd0[tt];
            #pragma unroll
            for (int p = 0; p < 8; ++p) if (lane == p + 1) val = topv[tt][p];
            qdsh[ctx][lane] = val;
        }
    }

    // gram for both contexts
    if (lane < 45) {
        const int a = PA[lane], b = PB[lane];
        #pragma unroll
        for (int tt = 0; tt < 2; ++tt) {
            const int ctx = w * 2 + tt;
            const float4* rka = (const float4*)&KshW[ctx][a][0];
            const float4* rkb = (const float4*)&KshW[ctx][b][0];
            float acc = 0.f;
            #pragma unroll
            for (int t = 0; t < 16; ++t) {
                float4 fa = rka[t], fb = rkb[t];
                acc += fa.x * fb.x; acc += fa.y * fb.y;
                acc += fa.z * fb.z; acc += fa.w * fb.w;
            }
            Gsh[ctx][a * 9 + b] = acc;
            Gsh[ctx][b * 9 + a] = acc;
        }
    }

    // combos (lanes 0..35)
    const int sl0c = (lane < NCOMB) ? C_SL0[lane] : -1;
    const int sl1c = (lane < NCOMB) ? C_SL1[lane] : -1;
    float score[2]; int ca[2], cb[2], sdim[2];
    #pragma unroll
    for (int tt = 0; tt < 2; ++tt) {
        const int ctx = w * 2 + tt;
        const int i = ii[tt];
        const int n_cand = (i + 1 < MTOP) ? (i + 1) : MTOP;
        int vmask = 0;
        #pragma unroll
        for (int s = 0; s < MTOP; ++s)
            if (s < n_cand && topi[tt][s] != i) vmask |= (1 << s);

        score[tt] = -INFINITY; ca[tt] = 0; cb[tt] = 0; sdim[tt] = 1;
        if (lane < NCOMB) {
            sdim[tt] = (sl1c < 0) ? 1 : 2;
            ca[tt] = sl0c + 1;
            cb[tt] = (sl1c < 0) ? 0 : sl1c + 1;
            bool valid = ((vmask >> sl0c) & 1);
            if (sdim[tt] == 2) valid = valid && ((vmask >> sl1c) & 1);
            float G00 = Gsh[ctx][0];
            float Gaa = Gsh[ctx][ca[tt] * 9 + ca[tt]];
            float G0a = Gsh[ctx][ca[tt]];
            float det;
            if (sdim[tt] == 1) {
                det = G00 * Gaa - G0a * G0a;
            } else {
                float G0b = Gsh[ctx][cb[tt]];
                float Gab = Gsh[ctx][ca[tt] * 9 + cb[tt]];
                float Gbb = Gsh[ctx][cb[tt] * 9 + cb[tt]];
                det = G00 * (Gaa * Gbb - Gab * Gab)
                    - G0a * (G0a * Gbb - Gab * G0b)
                    + G0b * (G0a * Gab - Gaa * G0b);
            }
            score[tt] = valid ? (logf(det + 1e-6f) / (float)(sdim[tt] + 1)) : NEGV;
        }
    }

    float mx[2] = {score[0], score[1]};
    #pragma unroll
    for (int off = 32; off > 0; off >>= 1)
        #pragma unroll
        for (int tt = 0; tt < 2; ++tt)
            mx[tt] = fmaxf(mx[tt], __shfl_xor(mx[tt], off, 64));
    float ee[2];
    #pragma unroll
    for (int tt = 0; tt < 2; ++tt)
        ee[tt] = (lane < NCOMB) ? expf(score[tt] - mx[tt]) : 0.f;
    float sum[2] = {ee[0], ee[1]};
    #pragma unroll
    for (int off = 32; off > 0; off >>= 1)
        #pragma unroll
        for (int tt = 0; tt < 2; ++tt)
            sum[tt] += __shfl_xor(sum[tt], off, 64);

    // per-lane prob-folded attention weights
    float pwx[2] = {0.f, 0.f}, pwy[2] = {0.f, 0.f}, pwz[2] = {0.f, 0.f};
    #pragma unroll
    for (int tt = 0; tt < 2; ++tt) {
        const int ctx = w * 2 + tt;
        if (lane < NCOMB) {
            float prob = ee[tt] / sum[tt];
            float d0 = qdsh[ctx][0]      * 0.125f;
            float d1 = qdsh[ctx][ca[tt]] * 0.125f;
            float d2 = (sdim[tt] == 2) ? qdsh[ctx][cb[tt]] * 0.125f : -INFINITY;
            float m2 = fmaxf(fmaxf(d0, d1), d2);
            float e0 = expf(d0 - m2), e1 = expf(d1 - m2);
            float e2 = (sdim[tt] == 2) ? expf(d2 - m2) : 0.f;
            float inv = prob / (e0 + e1 + e2);
            pwx[tt] = e0 * inv; pwy[tt] = e1 * inv; pwz[tt] = e2 * inv;
        }
    }

    // coefficient collapse: y = c0*V0 + sum_s cs[s]*V[s+1]
    float c0[2]; float cs[2][8];
    #pragma unroll
    for (int tt = 0; tt < 2; ++tt) {
        c0[tt] = pwx[tt];
        #pragma unroll
        for (int s = 0; s < 8; ++s)
            cs[tt][s] = ((sl0c == s) ? pwy[tt] : 0.f) + ((sl1c == s) ? pwz[tt] : 0.f);
    }
    #pragma unroll
    for (int off = 32; off > 0; off >>= 1) {
        #pragma unroll
        for (int tt = 0; tt < 2; ++tt) {
            c0[tt] += __shfl_xor(c0[tt], off, 64);
            #pragma unroll
            for (int s = 0; s < 8; ++s)
                cs[tt][s] += __shfl_xor(cs[tt][s], off, 64);
        }
    }

    // y for both contexts (9 LDS b32 reads each)
    #pragma unroll
    for (int tt = 0; tt < 2; ++tt) {
        const int ctx = w * 2 + tt;
        const bool hasValid = (mx[tt] > -1e29f);
        const float v0 = VshW[ctx][0][lane];
        float y = v0;
        if (hasValid) {
            y = c0[tt] * v0;
            #pragma unroll
            for (int s = 0; s < 8; ++s)
                y += cs[tt][s] * VshW[ctx][s + 1][lane];
        }
        const int bb = bh / Hn, h = bh % Hn;
        yb[((size_t)(bb * Tn + ii[tt])) * Cn + h * HS + lane] = bf_rne(y);
    }
}

extern "C" void kernel_launch(void* const* d_in, const int* in_sizes, int n_in,
                              void* d_out, int out_size, void* d_ws, size_t ws_size,
                              hipStream_t stream) {
    const float* x      = (const float*)d_in[0];
    const float* W_attn = (const float*)d_in[1];
    const float* b_attn = (const float*)d_in[2];
    const float* W_proj = (const float*)d_in[3];
    const float* b_proj = (const float*)d_in[4];
    float* out = (float*)d_out;

    char* ws = (char*)d_ws;
    float* vh            = (float*)(ws);                          //  0        3 MB
    unsigned short* qcat = (unsigned short*)(ws + 3145728);       //  3 MB     9 MB
    unsigned short* kcat = (unsigned short*)(ws + 12582912);      // 12 MB     9 MB
    unsigned short* xcat = (unsigned short*)(ws + 22020096);      // 21 MB     4.5 MB (dead after qkv)
    unsigned short* Wcat = (unsigned short*)(ws + 26738688);      // 25.5 MB  10.125 MB (dead after qkv)
    float* S             = (float*)(ws + 26738688);               // overlays Wcat, 13.5 MB
    unsigned short* ybf  = xcat;                                  // overlays xcat after qkv
    unsigned short* Wpbf = (unsigned short*)(ws + 40894464);      // 39 MB     1.125 MB -> 40.1 MB total

    // 1) all conversions in one launch (xcat | Wcat | Wpbf)
    conv_all<<<dim3((NX + NW + NP + 255) / 256), 256, 0, stream>>>(
        x, W_attn, W_proj, xcat, Wcat, Wpbf);

    // 2) fused qkv: q/k 3-term (by<24) + v 1-term (by>=24)
    mfma_qkv<<<dim3(16, 36), 256, 0, stream>>>(xcat, Wcat, b_attn, qcat, kcat, vh);

    // 3) S = qcat @ kcat^T (K'=384, 6-term split), lower-triangle tiles, packed store
    mfma_sim<<<dim3(36, BH), 256, 0, stream>>>(qcat, kcat, S);

    // 4) dpp: two tokens per wave, merge-based top-8, coef-collapsed epilogue
    dpp_kernel<<<dim3(BH, Tn / 8), 256, 0, stream>>>(S, kcat, vh, ybf);

    // 5) out = y @ Wp^T + bias
    mfma_proj<<<dim3(16, 12), 256, 0, stream>>>(ybf, Wpbf, b_proj, out);
}

// Round 15
// 151.795 us; speedup vs baseline: 3.2291x; 1.1136x over previous
//
#include <hip/hip_runtime.h>
#include <math.h>

#define Bn 2
#define Hn 12
#define Tn 512
#define Cn 768
#define HS 64
#define BH 24
#define MTOP 8
#define NCOMB 36
#define NEGV -1e30f

#define NX (Bn * Tn * Cn)     // 786432
#define NW (3 * Cn * Cn)      // 1769472
#define NP (Cn * Cn)          // 589824

typedef __bf16 bf16x8 __attribute__((ext_vector_type(8)));
typedef float f32x4 __attribute__((ext_vector_type(4)));

__device__ __constant__ int C_SL0[NCOMB] = {
  0,1,2,3,4,5,6,7,
  0,0,0,0,0,0,0,
  1,1,1,1,1,1,
  2,2,2,2,2,
  3,3,3,3,
  4,4,4,
  5,5,
  6};
__device__ __constant__ int C_SL1[NCOMB] = {
  -1,-1,-1,-1,-1,-1,-1,-1,
  1,2,3,4,5,6,7,
  2,3,4,5,6,7,
  3,4,5,6,7,
  4,5,6,7,
  5,6,7,
  6,7,
  7};

__device__ __constant__ int PA[45] = {
  0,0,0,0,0,0,0,0,0,
  1,1,1,1,1,1,1,1,
  2,2,2,2,2,2,2,
  3,3,3,3,3,3,
  4,4,4,4,4,
  5,5,5,5,
  6,6,6,
  7,7,
  8};
__device__ __constant__ int PB[45] = {
  0,1,2,3,4,5,6,7,8,
  1,2,3,4,5,6,7,8,
  2,3,4,5,6,7,8,
  3,4,5,6,7,8,
  4,5,6,7,8,
  5,6,7,8,
  6,7,8,
  7,8,
  8};

// lower-triangle 8x8 tile enumeration (ti >= tj)
__device__ __constant__ int TI[36] = {
  0,1,1,2,2,2,3,3,3,3,4,4,4,4,4,5,5,5,5,5,5,6,6,6,6,6,6,6,7,7,7,7,7,7,7,7};
__device__ __constant__ int TJ[36] = {
  0,0,1,0,1,2,0,1,2,3,0,1,2,3,4,0,1,2,3,4,5,0,1,2,3,4,5,6,0,1,2,3,4,5,6,7};

__device__ __forceinline__ unsigned short bf_rne(float x) {
    unsigned u = __float_as_uint(x);
    return (unsigned short)((u + 0x7fff + ((u >> 16) & 1)) >> 16);
}
__device__ __forceinline__ float bf_f(unsigned short s) {
    return __uint_as_float(((unsigned)s) << 16);
}

// ---- DPP wave64 reductions (VALU pipe — zero LDS traffic) ----------------------------
// row_shr:k = 0x110+k, row_bcast15 = 0x142, row_bcast31 = 0x143.
// update_dpp: masked/invalid lanes yield `old` (= identity).
template<int CTRL, int RM>
__device__ __forceinline__ float dpp_add_step(float x) {
    int t = __builtin_amdgcn_update_dpp(0, __float_as_int(x), CTRL, RM, 0xf, false);
    return x + __int_as_float(t);
}
template<int CTRL, int RM>
__device__ __forceinline__ float dpp_max_step(float x) {
    int t = __builtin_amdgcn_update_dpp((int)0xFF800000, __float_as_int(x), CTRL, RM, 0xf, false);
    return fmaxf(x, __int_as_float(t));
}
__device__ __forceinline__ float wave_sum(float x) {
    x = dpp_add_step<0x111, 0xf>(x);
    x = dpp_add_step<0x112, 0xf>(x);
    x = dpp_add_step<0x114, 0xf>(x);
    x = dpp_add_step<0x118, 0xf>(x);
    x = dpp_add_step<0x142, 0xa>(x);
    x = dpp_add_step<0x143, 0xc>(x);
    return __int_as_float(__builtin_amdgcn_readlane(__float_as_int(x), 63));
}
__device__ __forceinline__ float wave_max(float x) {
    x = dpp_max_step<0x111, 0xf>(x);
    x = dpp_max_step<0x112, 0xf>(x);
    x = dpp_max_step<0x114, 0xf>(x);
    x = dpp_max_step<0x118, 0xf>(x);
    x = dpp_max_step<0x142, 0xa>(x);
    x = dpp_max_step<0x143, 0xc>(x);
    return __int_as_float(__builtin_amdgcn_readlane(__float_as_int(x), 63));
}

// ---- fused conversions: xcat | Wcat | Wpbf in one launch -----------------------------
__global__ __launch_bounds__(256) void conv_all(const float* __restrict__ x,
                                                const float* __restrict__ Wa,
                                                const float* __restrict__ Wp,
                                                unsigned short* __restrict__ xcat,
                                                unsigned short* __restrict__ Wcat,
                                                unsigned short* __restrict__ Wpbf) {
    int idx = blockIdx.x * 256 + threadIdx.x;
    if (idx < NX) {
        int r = idx / Cn, c = idx - r * Cn;
        float v = x[idx];
        unsigned short h = bf_rne(v);
        unsigned short l = bf_rne(v - bf_f(h));
        size_t base = (size_t)r * 2304 + c;
        xcat[base] = h;            // [xhi | xhi | xlo]
        xcat[base + 768] = h;
        xcat[base + 1536] = l;
    } else if (idx < NX + NW) {
        int j = idx - NX;
        int r = j / Cn, c = j - r * Cn;
        float v = Wa[j];
        unsigned short h = bf_rne(v);
        unsigned short l = bf_rne(v - bf_f(h));
        size_t base = (size_t)r * 2304 + c;
        Wcat[base] = h;            // [Whi | Wlo | Whi]
        Wcat[base + 1536] = h;
        Wcat[base + 768] = l;
    } else if (idx < NX + NW + NP) {
        int j = idx - NX - NW;
        Wpbf[j] = bf_rne(Wp[j]);
    }
}

// ---- shared LDS-staged bf16 NT GEMM core, depth-2 prefetch (named reg sets) ----------
__device__ __forceinline__ void gemm_core(const unsigned short* __restrict__ Ag,
                                          const unsigned short* __restrict__ Bg,
                                          int Kst, int NS,
                                          unsigned short* Ab, unsigned short* Bb,
                                          f32x4 acc[2][2]) {
    const int tid = threadIdx.x;
    const int wv = tid >> 6, lane = tid & 63;
    const int r0 = tid >> 3;
    const int c8 = (tid & 7) * 8;
    const int m0w = (wv >> 1) * 32;
    const int n0w = (wv & 1) * 32;
    const int fr = lane & 15;
    const int fk = (lane >> 4) * 8;

    const unsigned short* pa0 = Ag + (size_t)r0 * Kst + c8;
    const unsigned short* pa1 = Ag + (size_t)(r0 + 32) * Kst + c8;
    const unsigned short* pb0 = Bg + (size_t)r0 * Kst + c8;
    const unsigned short* pb1 = Bg + (size_t)(r0 + 32) * Kst + c8;

    bf16x8 raA0 = *(const bf16x8*)pa0;
    bf16x8 raA1 = *(const bf16x8*)pa1;
    bf16x8 rbA0 = *(const bf16x8*)pb0;
    bf16x8 rbA1 = *(const bf16x8*)pb1;
    bf16x8 raB0 = *(const bf16x8*)(pa0 + 64);
    bf16x8 raB1 = *(const bf16x8*)(pa1 + 64);
    bf16x8 rbB0 = *(const bf16x8*)(pb0 + 64);
    bf16x8 rbB1 = *(const bf16x8*)(pb1 + 64);

    const int sO = r0 * 72 + c8;

    auto compute = [&](int bufo) {
        #pragma unroll
        for (int ks = 0; ks < 2; ++ks) {
            bf16x8 af[2], bg[2];
            #pragma unroll
            for (int mi = 0; mi < 2; ++mi)
                af[mi] = *(const bf16x8*)(Ab + bufo + (m0w + 16 * mi + fr) * 72 + ks * 32 + fk);
            #pragma unroll
            for (int ni = 0; ni < 2; ++ni)
                bg[ni] = *(const bf16x8*)(Bb + bufo + (n0w + 16 * ni + fr) * 72 + ks * 32 + fk);
            #pragma unroll
            for (int mi = 0; mi < 2; ++mi)
                #pragma unroll
                for (int ni = 0; ni < 2; ++ni)
                    acc[mi][ni] = __builtin_amdgcn_mfma_f32_16x16x32_bf16(af[mi], bg[ni], acc[mi][ni], 0, 0, 0);
        }
    };

    for (int s = 0; s < NS; s += 2) {
        *(bf16x8*)(Ab + sO)           = raA0;
        *(bf16x8*)(Ab + sO + 32 * 72) = raA1;
        *(bf16x8*)(Bb + sO)           = rbA0;
        *(bf16x8*)(Bb + sO + 32 * 72) = rbA1;
        __syncthreads();
        if (s + 2 < NS) {
            raA0 = *(const bf16x8*)(pa0 + (s + 2) * 64);
            raA1 = *(const bf16x8*)(pa1 + (s + 2) * 64);
            rbA0 = *(const bf16x8*)(pb0 + (s + 2) * 64);
            rbA1 = *(const bf16x8*)(pb1 + (s + 2) * 64);
        }
        compute(0);

        *(bf16x8*)(Ab + 4608 + sO)           = raB0;
        *(bf16x8*)(Ab + 4608 + sO + 32 * 72) = raB1;
        *(bf16x8*)(Bb + 4608 + sO)           = rbB0;
        *(bf16x8*)(Bb + 4608 + sO + 32 * 72) = rbB1;
        __syncthreads();
        if (s + 3 < NS) {
            raB0 = *(const bf16x8*)(pa0 + (s + 3) * 64);
            raB1 = *(const bf16x8*)(pa1 + (s + 3) * 64);
            rbB0 = *(const bf16x8*)(pb0 + (s + 3) * 64);
            rbB1 = *(const bf16x8*)(pb1 + (s + 3) * 64);
        }
        compute(4608);
    }
}

// ---- qkv fused: by<24 -> q/k 3-term GEMM (K'=2304); by>=24 -> v 1-term (K=768) -------
__global__ __launch_bounds__(256) void mfma_qkv(const unsigned short* __restrict__ xcat,
                                                const unsigned short* __restrict__ Wcat,
                                                const float* __restrict__ bias,
                                                unsigned short* __restrict__ qcat,
                                                unsigned short* __restrict__ kcat,
                                                float* __restrict__ vh) {
    __shared__ unsigned short Ab[2 * 64 * 72];
    __shared__ unsigned short Bb[2 * 64 * 72];
    const int tm = blockIdx.x * 64;
    const int by = blockIdx.y;
    const int wv = threadIdx.x >> 6, lane = threadIdx.x & 63;
    const int kq = lane >> 4, r = lane & 15;
    f32x4 acc[2][2] = {};

    if (by < 24) {
        const int tn = by * 64;
        gemm_core(xcat + (size_t)tm * 2304, Wcat + (size_t)tn * 2304, 2304, 36, Ab, Bb, acc);
        const int part = tn / Cn;          // 0=q, 1=k
        #pragma unroll
        for (int mi = 0; mi < 2; ++mi) {
            #pragma unroll
            for (int ni = 0; ni < 2; ++ni) {
                #pragma unroll
                for (int rr = 0; rr < 4; ++rr) {
                    int mm = tm + (wv >> 1) * 32 + mi * 16 + kq * 4 + rr;
                    int nn = tn + (wv & 1) * 32 + ni * 16 + r;
                    float val = acc[mi][ni][rr] + bias[nn];
                    int bb = mm >> 9, t = mm & 511;
                    int c = nn - part * Cn;
                    int h = c >> 6, d = c & 63;
                    int bh = bb * Hn + h;
                    unsigned short s1 = bf_rne(val);
                    float r1 = val - bf_f(s1);
                    unsigned short s2 = bf_rne(r1);
                    unsigned short s3 = bf_rne(r1 - bf_f(s2));
                    size_t base = ((size_t)bh * Tn + t) * 384 + d;
                    if (part == 0) {   // qcat = [q1|q1|q2|q1|q3|q2]
                        qcat[base]       = s1;
                        qcat[base + 64]  = s1;
                        qcat[base + 192] = s1;
                        qcat[base + 128] = s2;
                        qcat[base + 320] = s2;
                        qcat[base + 256] = s3;
                    } else {           // kcat = [k1|k2|k1|k3|k1|k2]
                        kcat[base]       = s1;
                        kcat[base + 128] = s1;
                        kcat[base + 256] = s1;
                        kcat[base + 64]  = s2;
                        kcat[base + 320] = s2;
                        kcat[base + 192] = s3;
                    }
                }
            }
        }
    } else {
        // v: single-term bf16 (xhi @ Wvhi^T), K extent 768 within stride-2304 rows
        const int hvi = by - 24;           // head-col tile 0..11
        const int cv = hvi * 64;
        gemm_core(xcat + (size_t)tm * 2304,
                  Wcat + (size_t)(1536 + cv) * 2304, 2304, 12, Ab, Bb, acc);
        #pragma unroll
        for (int mi = 0; mi < 2; ++mi) {
            #pragma unroll
            for (int ni = 0; ni < 2; ++ni) {
                #pragma unroll
                for (int rr = 0; rr < 4; ++rr) {
                    int mm = tm + (wv >> 1) * 32 + mi * 16 + kq * 4 + rr;
                    int nloc = (wv & 1) * 32 + ni * 16 + r;      // 0..63 == d
                    float val = acc[mi][ni][rr] + bias[1536 + cv + nloc];
                    int bb = mm >> 9, t = mm & 511;
                    int bh = bb * Hn + hvi;
                    vh[((size_t)bh * Tn + t) * HS + nloc] = val;
                }
            }
        }
    }
}

// ---- sim: S = qcat @ kcat^T per bh (K'=384 = 6-term split), triangle tiles -----------
__global__ __launch_bounds__(256) void mfma_sim(const unsigned short* __restrict__ qcat,
                                                const unsigned short* __restrict__ kcat,
                                                float* __restrict__ S) {
    __shared__ unsigned short Ab[2 * 64 * 72];
    __shared__ unsigned short Bb[2 * 64 * 72];
    const int bh = blockIdx.y;
    const int ti = TI[blockIdx.x], tj = TJ[blockIdx.x];
    f32x4 acc[2][2] = {};
    gemm_core(qcat + ((size_t)bh * Tn + ti * 64) * 384,
              kcat + ((size_t)bh * Tn + tj * 64) * 384, 384, 6, Ab, Bb, acc);

    const int wv = threadIdx.x >> 6, lane = threadIdx.x & 63;
    const int kq = lane >> 4, r = lane & 15;
    float* Sp = S + (size_t)bh * 147456 + (size_t)(ti * (ti + 1) / 2 + tj) * 4096;
    #pragma unroll
    for (int mi = 0; mi < 2; ++mi)
        #pragma unroll
        for (int ni = 0; ni < 2; ++ni)
            #pragma unroll
            for (int rr = 0; rr < 4; ++rr) {
                int ml = (wv >> 1) * 32 + mi * 16 + kq * 4 + rr;
                int nl = (wv & 1) * 32 + ni * 16 + r;
                Sp[ml * 64 + nl] = acc[mi][ni][rr];
            }
}

// ---- proj: out = ybf @ Wpbf^T + bias (K=768) -----------------------------------------
__global__ __launch_bounds__(256) void mfma_proj(const unsigned short* __restrict__ Abf,
                                                 const unsigned short* __restrict__ Bbf,
                                                 const float* __restrict__ bias,
                                                 float* __restrict__ outp) {
    __shared__ unsigned short Ab[2 * 64 * 72];
    __shared__ unsigned short Bb[2 * 64 * 72];
    const int tm = blockIdx.x * 64;
    const int tn = blockIdx.y * 64;
    f32x4 acc[2][2] = {};
    gemm_core(Abf + (size_t)tm * Cn, Bbf + (size_t)tn * Cn, Cn, 12, Ab, Bb, acc);

    const int wv = threadIdx.x >> 6, lane = threadIdx.x & 63;
    const int kq = lane >> 4, r = lane & 15;
    #pragma unroll
    for (int mi = 0; mi < 2; ++mi)
        #pragma unroll
        for (int ni = 0; ni < 2; ++ni)
            #pragma unroll
            for (int rr = 0; rr < 4; ++rr) {
                int mm = tm + (wv >> 1) * 32 + mi * 16 + kq * 4 + rr;
                int nn = tn + (wv & 1) * 32 + ni * 16 + r;
                outp[(size_t)mm * Cn + nn] = acc[mi][ni][rr] + bias[nn];
            }
}

// float compare-exchange, descending (larger to lower index)
#define CEF(arr, ia, ib) { \
    float _a = arr[ia], _b = arr[ib]; \
    arr[ia] = fmaxf(_a, _b); arr[ib] = fminf(_a, _b); }

// ---- DPP selection: TWO tokens per wave; value-merge top-8 + ballot index recovery;
// all scalar reductions on the VALU pipe via DPP (r14 lesson: dpp is LDS-pipe-bound) --
__global__ __launch_bounds__(256) void dpp_kernel(const float* __restrict__ S,
                                                  const unsigned short* __restrict__ kcat,
                                                  const float* __restrict__ vh,
                                                  unsigned short* __restrict__ yb) {
    const int bh = blockIdx.x;
    const int w = threadIdx.x >> 6;
    const int lane = threadIdx.x & 63;
    const int ibase = blockIdx.y * 8 + w * 2;

    __shared__ float KshW[8][9][68];   // 19584 B
    __shared__ float VshW[8][9][65];   // 18720 B
    __shared__ float Gsh[8][81];       //  2592 B
    __shared__ float qdsh[8][12];      //   384 B  -> 41280 B total
    const float* Sbh = S + (size_t)bh * 147456;
    const unsigned short* kc = kcat + (size_t)bh * Tn * 384;
    const float* vbase = vh + (size_t)bh * Tn * HS;

    int ii[2], tib[2];
    float sv[2][8];
    float qd0[2];
    #pragma unroll
    for (int tt = 0; tt < 2; ++tt) {
        const int i = ibase + tt;
        ii[tt] = i;
        const int t8 = i >> 6;
        tib[tt] = t8;
        const int tribase = t8 * (t8 + 1) / 2;
        const int rloc = (i & 63) * 64;
        #pragma unroll
        for (int rr = 0; rr < 8; ++rr) {
            sv[tt][rr] = -INFINITY;
            if (rr <= t8) {
                int j = rr * 64 + lane;
                float s = Sbh[(size_t)(tribase + rr) * 4096 + rloc + lane];
                sv[tt][rr] = (j <= i) ? s : -INFINITY;
            }
        }
        // qd0 = S[i][i] loaded directly (same addr all lanes -> broadcast)
        qd0[tt] = Sbh[(size_t)(tribase + t8) * 4096 + rloc + (i & 63)];
    }

    // ---- top-8 VALUES via sorted merge (32-bit, 1 shuffle per key) -------------------
    float key[2][8];
    #pragma unroll
    for (int tt = 0; tt < 2; ++tt)
        #pragma unroll
        for (int r = 0; r < 8; ++r) key[tt][r] = sv[tt][r];

    // per-lane Batcher odd-even mergesort 8 (descending) — pure VALU
    #pragma unroll
    for (int tt = 0; tt < 2; ++tt) {
        CEF(key[tt],0,1) CEF(key[tt],2,3) CEF(key[tt],4,5) CEF(key[tt],6,7)
        CEF(key[tt],0,2) CEF(key[tt],1,3) CEF(key[tt],4,6) CEF(key[tt],5,7)
        CEF(key[tt],1,2) CEF(key[tt],5,6)
        CEF(key[tt],0,4) CEF(key[tt],1,5) CEF(key[tt],2,6) CEF(key[tt],3,7)
        CEF(key[tt],2,4) CEF(key[tt],3,5)
        CEF(key[tt],1,2) CEF(key[tt],3,4) CEF(key[tt],5,6)
    }

    // 6 butterfly merge stages (values only): top-8 of self U partner
    #pragma unroll
    for (int st = 0; st < 6; ++st) {
        const int off = 1 << st;
        #pragma unroll
        for (int tt = 0; tt < 2; ++tt) {
            float pk[8];
            #pragma unroll
            for (int r = 0; r < 8; ++r)
                pk[r] = __shfl_xor(key[tt][r], off, 64);
            float t[8];
            #pragma unroll
            for (int r = 0; r < 8; ++r)
                t[r] = fmaxf(key[tt][r], pk[7 - r]);       // bitonic half-cleaner
            CEF(t,0,4) CEF(t,1,5) CEF(t,2,6) CEF(t,3,7)
            CEF(t,0,2) CEF(t,1,3) CEF(t,4,6) CEF(t,5,7)
            CEF(t,0,1) CEF(t,2,3) CEF(t,4,5) CEF(t,6,7)
            #pragma unroll
            for (int r = 0; r < 8; ++r) key[tt][r] = t[r];
        }
    }
    // all lanes now hold identical sorted top-8 values key[tt][0..7]

    // ---- exact index recovery: (v desc, idx asc) incl. duplicates, via ballot --------
    int topi[2][8];
    float topv[2][8];
    #pragma unroll
    for (int tt = 0; tt < 2; ++tt) {
        unsigned long long used[8] = {0, 0, 0, 0, 0, 0, 0, 0};
        #pragma unroll
        for (int p = 0; p < 8; ++p) {
            float v = key[tt][p];
            topv[tt][p] = v;
            int idx = ii[tt];              // safe in-range fallback (unreachable)
            bool found = false;
            #pragma unroll
            for (int r = 0; r < 8; ++r) {
                unsigned long long m = __ballot(sv[tt][r] == v) & ~used[r];
                if (!found && m != 0ull) {
                    int l = __builtin_ctzll(m);
                    idx = r * 64 + l;      // reg-major == global index order
                    used[r] |= (1ull << l);
                    found = true;
                }
            }
            topi[tt][p] = idx;
        }
    }

    // stage K/V rows for both contexts
    #pragma unroll
    for (int tt = 0; tt < 2; ++tt) {
        const int ctx = w * 2 + tt;
        #pragma unroll
        for (int a = 0; a < 9; ++a) {
            int t = (a == 0) ? ii[tt] : topi[tt][a - 1];
            size_t kb = (size_t)t * 384 + lane;
            KshW[ctx][a][lane] = bf_f(kc[kb]) + bf_f(kc[kb + 64]) + bf_f(kc[kb + 192]);
            VshW[ctx][a][lane] = vbase[(size_t)t * HS + lane];
        }
        if (lane < 9) {
            float val = qd0[tt];
            #pragma unroll
            for (int p = 0; p < 8; ++p) if (lane == p + 1) val = topv[tt][p];
            qdsh[ctx][lane] = val;
        }
    }

    // gram for both contexts
    if (lane < 45) {
        const int a = PA[lane], b = PB[lane];
        #pragma unroll
        for (int tt = 0; tt < 2; ++tt) {
            const int ctx = w * 2 + tt;
            const float4* rka = (const float4*)&KshW[ctx][a][0];
            const float4* rkb = (const float4*)&KshW[ctx][b][0];
            float acc = 0.f;
            #pragma unroll
            for (int t = 0; t < 16; ++t) {
                float4 fa = rka[t], fb = rkb[t];
                acc += fa.x * fb.x; acc += fa.y * fb.y;
                acc += fa.z * fb.z; acc += fa.w * fb.w;
            }
            Gsh[ctx][a * 9 + b] = acc;
            Gsh[ctx][b * 9 + a] = acc;
        }
    }

    // combos (lanes 0..35)
    const int sl0c = (lane < NCOMB) ? C_SL0[lane] : -1;
    const int sl1c = (lane < NCOMB) ? C_SL1[lane] : -1;
    float score[2]; int ca[2], cb[2], sdim[2];
    #pragma unroll
    for (int tt = 0; tt < 2; ++tt) {
        const int ctx = w * 2 + tt;
        const int i = ii[tt];
        const int n_cand = (i + 1 < MTOP) ? (i + 1) : MTOP;
        int vmask = 0;
        #pragma unroll
        for (int s = 0; s < MTOP; ++s)
            if (s < n_cand && topi[tt][s] != i) vmask |= (1 << s);

        score[tt] = -INFINITY; ca[tt] = 0; cb[tt] = 0; sdim[tt] = 1;
        if (lane < NCOMB) {
            sdim[tt] = (sl1c < 0) ? 1 : 2;
            ca[tt] = sl0c + 1;
            cb[tt] = (sl1c < 0) ? 0 : sl1c + 1;
            bool valid = ((vmask >> sl0c) & 1);
            if (sdim[tt] == 2) valid = valid && ((vmask >> sl1c) & 1);
            float G00 = Gsh[ctx][0];
            float Gaa = Gsh[ctx][ca[tt] * 9 + ca[tt]];
            float G0a = Gsh[ctx][ca[tt]];
            float det;
            if (sdim[tt] == 1) {
                det = G00 * Gaa - G0a * G0a;
            } else {
                float G0b = Gsh[ctx][cb[tt]];
                float Gab = Gsh[ctx][ca[tt] * 9 + cb[tt]];
                float Gbb = Gsh[ctx][cb[tt] * 9 + cb[tt]];
                det = G00 * (Gaa * Gbb - Gab * Gab)
                    - G0a * (G0a * Gbb - Gab * G0b)
                    + G0b * (G0a * Gab - Gaa * G0b);
            }
            score[tt] = valid ? (logf(det + 1e-6f) / (float)(sdim[tt] + 1)) : NEGV;
        }
    }

    // softmax over scores: DPP reductions (VALU pipe)
    float mxv[2], sumv[2], ee[2];
    #pragma unroll
    for (int tt = 0; tt < 2; ++tt) mxv[tt] = wave_max(score[tt]);
    #pragma unroll
    for (int tt = 0; tt < 2; ++tt)
        ee[tt] = (lane < NCOMB) ? expf(score[tt] - mxv[tt]) : 0.f;
    #pragma unroll
    for (int tt = 0; tt < 2; ++tt) sumv[tt] = wave_sum(ee[tt]);

    // per-lane prob-folded attention weights
    float pwx[2] = {0.f, 0.f}, pwy[2] = {0.f, 0.f}, pwz[2] = {0.f, 0.f};
    #pragma unroll
    for (int tt = 0; tt < 2; ++tt) {
        const int ctx = w * 2 + tt;
        if (lane < NCOMB) {
            float prob = ee[tt] / sumv[tt];
            float d0 = qdsh[ctx][0]      * 0.125f;
            float d1 = qdsh[ctx][ca[tt]] * 0.125f;
            float d2 = (sdim[tt] == 2) ? qdsh[ctx][cb[tt]] * 0.125f : -INFINITY;
            float m2 = fmaxf(fmaxf(d0, d1), d2);
            float e0 = expf(d0 - m2), e1 = expf(d1 - m2);
            float e2 = (sdim[tt] == 2) ? expf(d2 - m2) : 0.f;
            float inv = prob / (e0 + e1 + e2);
            pwx[tt] = e0 * inv; pwy[tt] = e1 * inv; pwz[tt] = e2 * inv;
        }
    }

    // coefficient collapse via DPP sums: y = c0*V0 + sum_s cs[s]*V[s+1]
    float c0[2], cs[2][8];
    #pragma unroll
    for (int tt = 0; tt < 2; ++tt) {
        c0[tt] = wave_sum(pwx[tt]);
        #pragma unroll
        for (int s = 0; s < 8; ++s) {
            float contrib = ((sl0c == s) ? pwy[tt] : 0.f) + ((sl1c == s) ? pwz[tt] : 0.f);
            cs[tt][s] = wave_sum(contrib);
        }
    }

    // y for both contexts (9 LDS b32 reads each)
    #pragma unroll
    for (int tt = 0; tt < 2; ++tt) {
        const int ctx = w * 2 + tt;
        const bool hasValid = (mxv[tt] > -1e29f);
        const float v0 = VshW[ctx][0][lane];
        float y = v0;
        if (hasValid) {
            y = c0[tt] * v0;
            #pragma unroll
            for (int s = 0; s < 8; ++s)
                y += cs[tt][s] * VshW[ctx][s + 1][lane];
        }
        const int bb = bh / Hn, h = bh % Hn;
        yb[((size_t)(bb * Tn + ii[tt])) * Cn + h * HS + lane] = bf_rne(y);
    }
}

extern "C" void kernel_launch(void* const* d_in, const int* in_sizes, int n_in,
                              void* d_out, int out_size, void* d_ws, size_t ws_size,
                              hipStream_t stream) {
    const float* x      = (const float*)d_in[0];
    const float* W_attn = (const float*)d_in[1];
    const float* b_attn = (const float*)d_in[2];
    const float* W_proj = (const float*)d_in[3];
    const float* b_proj = (const float*)d_in[4];
    float* out = (float*)d_out;

    char* ws = (char*)d_ws;
    float* vh            = (float*)(ws);                          //  0        3 MB
    unsigned short* qcat = (unsigned short*)(ws + 3145728);       //  3 MB     9 MB
    unsigned short* kcat = (unsigned short*)(ws + 12582912);      // 12 MB     9 MB
    unsigned short* xcat = (unsigned short*)(ws + 22020096);      // 21 MB     4.5 MB (dead after qkv)
    unsigned short* Wcat = (unsigned short*)(ws + 26738688);      // 25.5 MB  10.125 MB (dead after qkv)
    float* S             = (float*)(ws + 26738688);               // overlays Wcat, 13.5 MB
    unsigned short* ybf  = xcat;                                  // overlays xcat after qkv
    unsigned short* Wpbf = (unsigned short*)(ws + 40894464);      // 39 MB     1.125 MB -> 40.1 MB total

    // 1) all conversions in one launch (xcat | Wcat | Wpbf)
    conv_all<<<dim3((NX + NW + NP + 255) / 256), 256, 0, stream>>>(
        x, W_attn, W_proj, xcat, Wcat, Wpbf);

    // 2) fused qkv: q/k 3-term (by<24) + v 1-term (by>=24)
    mfma_qkv<<<dim3(16, 36), 256, 0, stream>>>(xcat, Wcat, b_attn, qcat, kcat, vh);

    // 3) S = qcat @ kcat^T (K'=384, 6-term split), lower-triangle tiles, packed store
    mfma_sim<<<dim3(36, BH), 256, 0, stream>>>(qcat, kcat, S);

    // 4) dpp: value-merge top-8 + ballot index recovery + DPP reductions
    dpp_kernel<<<dim3(BH, Tn / 8), 256, 0, stream>>>(S, kcat, vh, ybf);

    // 5) out = y @ Wp^T + bias
    mfma_proj<<<dim3(16, 12), 256, 0, stream>>>(ybf, Wpbf, b_proj, out);
}